// Round 2
// baseline (23996.213 us; speedup 1.0000x reference)
//
#include <hip/hip_runtime.h>

// ErbStage: conv0+LN+ReLU -> conv1+LN+ReLU -> spectral attention -> GRU(T=1000)
//           -> GRU(B=32 scan) + lsnr -> LN/conv2/LN/sigmoid mask.
//
// Workspace plan (adaptive to ws_size):
//   x1g  [32000,256] bf16   16.4 MB   (frontend -> final)
//   ob   [32000,256] bf16   16.4 MB   (gru_batch -> gru_snr/final)
//   gih  [GB*1000,768] bf16 <=49.2 MB (gemm -> gru_batch), GB in {32,16,8,4,2,1}
//   gi   [CH,2048]   bf16   <=26.2 MB (frontend -> gemm staging chunk)
// Total <= ~108.5 MB at GB=32; ~40 MB at GB=1.

typedef unsigned short u16;
typedef u16 u16x8 __attribute__((ext_vector_type(8)));

__device__ __forceinline__ float sigf(float x) { return 1.f / (1.f + __expf(-x)); }
__device__ __forceinline__ float tanhfast(float x) { return 2.f / (1.f + __expf(-2.f * x)) - 1.f; }
__device__ __forceinline__ float bf2f(u16 s) { union { unsigned u; float f; } x; x.u = ((unsigned)s) << 16; return x.f; }
__device__ __forceinline__ u16 f2bf(float f) {
  union { float f; unsigned u; } x; x.f = f;
  unsigned r = x.u + 0x7fffu + ((x.u >> 16) & 1u);
  return (u16)(r >> 16);
}

// ---------------------------------------------------------------------------
// K1: fused frontend per (b,t): conv0+LN+ReLU -> conv1+LN+ReLU (store x1 bf16)
//     -> q/k/v 1x3 convs -> QK^T/8 -> joint softmax(1024) -> att*V -> gi (bf16)
// ---------------------------------------------------------------------------
__global__ __launch_bounds__(256) void k_frontend(
    const float* __restrict__ in,
    const float* __restrict__ w0c, const float* __restrict__ b0c,
    const float* __restrict__ g0, const float* __restrict__ be0,
    const float* __restrict__ w1c, const float* __restrict__ b1c,
    const float* __restrict__ g1, const float* __restrict__ be1,
    const float* __restrict__ qw, const float* __restrict__ qb,
    const float* __restrict__ kw, const float* __restrict__ kb,
    const float* __restrict__ vw, const float* __restrict__ vb,
    int bt0, u16* __restrict__ x1g, u16* __restrict__ gi)
{
  const int bt = bt0 + blockIdx.x, tid = threadIdx.x;
  __shared__ float s_in[34];
  __shared__ float s_x0[16][34];
  __shared__ float s_x1[8][34];
  __shared__ float s_q[64][32];
  __shared__ float s_k[64][32];
  __shared__ float s_v[32][64];
  __shared__ float s_sc[32][32];
  __shared__ float s_red[8];
  __shared__ float s_mu[16], s_rs[16];

  if (tid < 32) s_in[1 + tid] = in[(size_t)bt * 32 + tid];
  if (tid == 0) { s_in[0] = 0.f; s_in[33] = 0.f; }
  __syncthreads();

  // conv0 (1->16)
  #pragma unroll
  for (int i = 0; i < 2; ++i) {
    int o = tid + i * 256, c = o >> 5, f = o & 31;
    float a = b0c[c] + w0c[c*3]*s_in[f] + w0c[c*3+1]*s_in[f+1] + w0c[c*3+2]*s_in[f+2];
    s_x0[c][1 + f] = a;
  }
  __syncthreads();
  // ln0 stats: 16 channels x 16 threads
  {
    int c = tid >> 4, i = tid & 15;
    float a = s_x0[c][1 + i], b = s_x0[c][17 + i];
    float s = a + b, ss = a * a + b * b;
    #pragma unroll
    for (int m = 8; m >= 1; m >>= 1) { s += __shfl_xor(s, m); ss += __shfl_xor(ss, m); }
    if (i == 0) { float mu = s * (1.f/32.f); s_mu[c] = mu; s_rs[c] = rsqrtf(ss * (1.f/32.f) - mu*mu + 1e-5f); }
  }
  __syncthreads();
  #pragma unroll
  for (int i = 0; i < 2; ++i) {
    int o = tid + i * 256, c = o >> 5, f = o & 31;
    float v = (s_x0[c][1 + f] - s_mu[c]) * s_rs[c] * g0[f] + be0[f];
    s_x0[c][1 + f] = fmaxf(v, 0.f);
  }
  if (tid < 16) { s_x0[tid][0] = 0.f; s_x0[tid][33] = 0.f; }
  __syncthreads();

  // conv1 (16->8) + ln1 + relu; one thread per (c1,f)
  {
    int c = tid >> 5, f = tid & 31;
    float a = b1c[c];
    #pragma unroll
    for (int cc = 0; cc < 16; ++cc) {
      const float* wr = w1c + (c * 16 + cc) * 3;
      a += wr[0]*s_x0[cc][f] + wr[1]*s_x0[cc][f+1] + wr[2]*s_x0[cc][f+2];
    }
    float s = a, ss = a * a;
    #pragma unroll
    for (int m = 16; m >= 1; m >>= 1) { s += __shfl_xor(s, m); ss += __shfl_xor(ss, m); }
    float mu = s * (1.f/32.f), rs = rsqrtf(ss * (1.f/32.f) - mu*mu + 1e-5f);
    float v = fmaxf((a - mu) * rs * g1[f] + be1[f], 0.f);
    s_x1[c][1 + f] = v;
    x1g[(size_t)bt * 256 + tid] = f2bf(v);
  }
  if (tid < 8) { s_x1[tid][0] = 0.f; s_x1[tid][33] = 0.f; }
  __syncthreads();

  // q/k/v convs (8->64 each). thread: h = tid>>2, fg = tid&3, 8 f's each
  {
    int h = tid >> 2, fg = tid & 3;
    float aq[8], ak[8], av[8];
    float qbv = qb[h], kbv = kb[h], vbv = vb[h];
    #pragma unroll
    for (int i = 0; i < 8; ++i) { aq[i] = qbv; ak[i] = kbv; av[i] = vbv; }
    #pragma unroll
    for (int c = 0; c < 8; ++c) {
      const float* qr = qw + (h * 8 + c) * 3;
      const float* kr = kw + (h * 8 + c) * 3;
      const float* vr = vw + (h * 8 + c) * 3;
      float q0 = qr[0], q1 = qr[1], q2 = qr[2];
      float k0 = kr[0], k1 = kr[1], k2 = kr[2];
      float v0 = vr[0], v1 = vr[1], v2 = vr[2];
      #pragma unroll
      for (int i = 0; i < 8; ++i) {
        int f = fg + i * 4;
        float xa = s_x1[c][f], xb = s_x1[c][f+1], xc = s_x1[c][f+2];
        aq[i] += q0*xa + q1*xb + q2*xc;
        ak[i] += k0*xa + k1*xb + k2*xc;
        av[i] += v0*xa + v1*xb + v2*xc;
      }
    }
    #pragma unroll
    for (int i = 0; i < 8; ++i) {
      int f = fg + i * 4;
      s_q[h][f] = aq[i];
      s_k[h][f] = ak[i];
      s_v[f][h] = av[i];
    }
  }
  __syncthreads();

  // scores w[f][g] = sum_h q[h][f]*k[h][g] / 8
  float sc[4];
  #pragma unroll
  for (int i = 0; i < 4; ++i) {
    int o = tid + i * 256, f = o >> 5, g = o & 31;
    float a = 0.f;
    #pragma unroll 8
    for (int h = 0; h < 64; ++h) a += s_q[h][f] * s_k[h][g];
    sc[i] = a * 0.125f;
  }
  // joint softmax over all 1024
  float mx = fmaxf(fmaxf(sc[0], sc[1]), fmaxf(sc[2], sc[3]));
  #pragma unroll
  for (int m = 32; m >= 1; m >>= 1) mx = fmaxf(mx, __shfl_xor(mx, m));
  if ((tid & 63) == 0) s_red[tid >> 6] = mx;
  __syncthreads();
  mx = fmaxf(fmaxf(s_red[0], s_red[1]), fmaxf(s_red[2], s_red[3]));
  float sm = 0.f;
  #pragma unroll
  for (int i = 0; i < 4; ++i) { sc[i] = __expf(sc[i] - mx); sm += sc[i]; }
  #pragma unroll
  for (int m = 32; m >= 1; m >>= 1) sm += __shfl_xor(sm, m);
  __syncthreads();
  if ((tid & 63) == 0) s_red[4 + (tid >> 6)] = sm;
  __syncthreads();
  float inv = 1.f / (s_red[4] + s_red[5] + s_red[6] + s_red[7]);
  #pragma unroll
  for (int i = 0; i < 4; ++i) {
    int o = tid + i * 256, f = o >> 5, g = o & 31;
    s_sc[f][g] = sc[i] * inv;
  }
  __syncthreads();

  // att[f][h] = sum_g w[f][g]*v[g][h] ; gi row local to chunk
  u16* gir = gi + (size_t)blockIdx.x * 2048;
  #pragma unroll
  for (int i = 0; i < 8; ++i) {
    int o = tid + i * 256, f = o >> 6, h = o & 63;
    float a = 0.f;
    #pragma unroll 8
    for (int g = 0; g < 32; ++g) a += s_sc[f][g] * s_v[g][h];
    gir[o] = f2bf(a);
  }
}

// ---------------------------------------------------------------------------
// K2: C[M,768](bf16) = A[M,2048](bf16) @ W[768,2048]^T(f32) + bias
// ---------------------------------------------------------------------------
__global__ __launch_bounds__(256) void k_gemm_bias(
    const u16* __restrict__ A, const float* __restrict__ W,
    const float* __restrict__ bias, u16* __restrict__ C, int M)
{
  const int K = 2048, N = 768;
  __shared__ float As[16][68];   // [k][row]
  __shared__ float Ws[16][68];
  const int tid = threadIdx.x;
  const int m0 = blockIdx.x * 64, n0 = blockIdx.y * 64;
  const int ty = tid >> 4, tx = tid & 15;
  const int lr = tid >> 2, lk = (tid & 3) * 4;
  float acc[4][4] = {};
  for (int k0 = 0; k0 < K; k0 += 16) {
    {
      int ar = m0 + lr;
      ushort4 av = make_ushort4(0, 0, 0, 0);
      if (ar < M) av = *(const ushort4*)(A + (size_t)ar * K + k0 + lk);
      As[lk + 0][lr] = bf2f(av.x);
      As[lk + 1][lr] = bf2f(av.y);
      As[lk + 2][lr] = bf2f(av.z);
      As[lk + 3][lr] = bf2f(av.w);
      float4 wv = *(const float4*)(W + (size_t)(n0 + lr) * K + k0 + lk);
      Ws[lk + 0][lr] = wv.x;
      Ws[lk + 1][lr] = wv.y;
      Ws[lk + 2][lr] = wv.z;
      Ws[lk + 3][lr] = wv.w;
    }
    __syncthreads();
    #pragma unroll
    for (int k = 0; k < 16; ++k) {
      float4 a = *(const float4*)&As[k][ty * 4];
      float4 b = *(const float4*)&Ws[k][tx * 4];
      float ar[4] = {a.x, a.y, a.z, a.w}, br[4] = {b.x, b.y, b.z, b.w};
      #pragma unroll
      for (int i = 0; i < 4; ++i)
        #pragma unroll
        for (int j = 0; j < 4; ++j) acc[i][j] += ar[i] * br[j];
    }
    __syncthreads();
  }
  #pragma unroll
  for (int i = 0; i < 4; ++i) {
    int m = m0 + ty * 4 + i;
    int n = n0 + tx * 4;
    if (m < M) {
      ushort4 o4;
      o4.x = f2bf(acc[i][0] + bias[n + 0]);
      o4.y = f2bf(acc[i][1] + bias[n + 1]);
      o4.z = f2bf(acc[i][2] + bias[n + 2]);
      o4.w = f2bf(acc[i][3] + bias[n + 3]);
      *(ushort4*)&C[(size_t)m * N + n] = o4;
    }
  }
}

// ---------------------------------------------------------------------------
// K3: main GRU over T=1000. Batch elements are independent -> one 1024-thread
//     block per b, NO grid sync. h double-buffered in LDS; whh (786KB f32)
//     streamed from L2 each step. Thread (u = tid>>2, part = tid&3): 64-k
//     slice per gate, reduced via shfl_xor(1,2).
// ---------------------------------------------------------------------------
__global__ __launch_bounds__(1024) void k_gru_batch(
    const u16* __restrict__ gih, const float* __restrict__ whh,
    const float* __restrict__ bhh, u16* __restrict__ ob,
    float* __restrict__ hatt, int b0)
{
  __shared__ float s_h[2][256];
  const int tid = threadIdx.x;
  const int u = tid >> 2, part = tid & 3;
  const int bl = blockIdx.x;     // local b within this group
  const int b = b0 + bl;         // global b
  if (tid < 256) s_h[0][tid] = 0.f;
  const float4* wr4 = (const float4*)(whh + (size_t)(      u) * 256 + part * 64);
  const float4* wz4 = (const float4*)(whh + (size_t)(256 + u) * 256 + part * 64);
  const float4* wn4 = (const float4*)(whh + (size_t)(512 + u) * 256 + part * 64);
  float bh_r = 0.f, bh_z = 0.f, bh_n = 0.f;
  if (part == 0) { bh_r = bhh[u]; bh_z = bhh[256 + u]; bh_n = bhh[512 + u]; }
  __syncthreads();
  int cur = 0;
  for (int t = 0; t < 1000; ++t) {
    const float* hrow = s_h[cur];
    const float4* h4 = (const float4*)(hrow + part * 64);
    float pr = 0.f, pz = 0.f, pn = 0.f;
    #pragma unroll 4
    for (int k4 = 0; k4 < 16; ++k4) {
      float4 hv = h4[k4];
      float4 wa = wr4[k4], wb = wz4[k4], wc = wn4[k4];
      pr += hv.x*wa.x + hv.y*wa.y + hv.z*wa.z + hv.w*wa.w;
      pz += hv.x*wb.x + hv.y*wb.y + hv.z*wb.z + hv.w*wb.w;
      pn += hv.x*wc.x + hv.y*wc.y + hv.z*wc.z + hv.w*wc.w;
    }
    pr += __shfl_xor(pr, 1); pr += __shfl_xor(pr, 2);
    pz += __shfl_xor(pz, 1); pz += __shfl_xor(pz, 2);
    pn += __shfl_xor(pn, 1); pn += __shfl_xor(pn, 2);
    if (part == 0) {
      const u16* gr_ = gih + ((size_t)bl * 1000 + t) * 768;
      float r = sigf(bf2f(gr_[u]) + pr + bh_r);
      float z = sigf(bf2f(gr_[256 + u]) + pz + bh_z);
      float n = tanhfast(bf2f(gr_[512 + u]) + r * (pn + bh_n));
      float hnew = (1.f - z) * n + z * hrow[u];
      s_h[cur ^ 1][u] = hnew;
      ob[((size_t)b * 1000 + t) * 256 + u] = f2bf(hnew);
      if (t == 999) hatt[b * 256 + u] = hnew;
    }
    __syncthreads();
    cur ^= 1;
  }
}

// ---------------------------------------------------------------------------
// K4: snr GRU scans over B=32 steps; batch dim = T (independent per t).
//     64 WGs x 16 t-rows, grus_wih LDS-stationary, lsnr fused.
// ---------------------------------------------------------------------------
__global__ __launch_bounds__(256) void k_gru_snr(
    const u16* __restrict__ ob, const float* __restrict__ wih,
    const float* __restrict__ whh, const float* __restrict__ bih,
    const float* __restrict__ bhh, const float* __restrict__ fcw,
    const float* __restrict__ fcb,
    float* __restrict__ lsnr_out, float* __restrict__ hsnr_out)
{
  __shared__ float s_wi[48][260];
  __shared__ float s_wh[48][20];
  __shared__ float s_o[16][260];
  __shared__ float s_h[16][20];
  const int tid = threadIdx.x, wg = blockIdx.x;
  const int n0 = wg * 16;
  for (int i = tid; i < 48 * 256; i += 256) s_wi[i >> 8][i & 255] = wih[i];
  for (int i = tid; i < 768; i += 256) s_wh[i >> 4][i & 15] = whh[i];
  const int n = tid >> 4, u = tid & 15;
  const bool valid = (n0 + n) < 1000;
  s_h[n][u] = 0.f;
  float hcur = 0.f;
  const float bi_r = bih[u], bi_z = bih[16 + u], bi_n = bih[32 + u];
  const float bh_r = bhh[u], bh_z = bhh[16 + u], bh_n = bhh[32 + u];
  const float fw = fcw[u], fb = fcb[0];
  __syncthreads();
  for (int step = 0; step < 32; ++step) {
    for (int i = tid; i < 512; i += 256) {
      int nn = i >> 5, c8 = (i & 31) * 8;
      int row = n0 + nn;
      if (row < 1000) {
        u16x8 v = *(const u16x8*)(ob + ((size_t)step * 1000 + row) * 256 + c8);
        #pragma unroll
        for (int j = 0; j < 8; ++j) s_o[nn][c8 + j] = bf2f(v[j]);
      } else {
        #pragma unroll
        for (int j = 0; j < 8; ++j) s_o[nn][c8 + j] = 0.f;
      }
    }
    __syncthreads();
    float gr = bi_r, gz = bi_z, gn = bi_n;
    {
      const float4* o4 = (const float4*)&s_o[n][0];
      const float4* wr = (const float4*)&s_wi[u][0];
      const float4* wz = (const float4*)&s_wi[16 + u][0];
      const float4* wn = (const float4*)&s_wi[32 + u][0];
      #pragma unroll 4
      for (int k4 = 0; k4 < 64; ++k4) {
        float4 ov = o4[k4];
        float4 a = wr[k4], c = wz[k4], d = wn[k4];
        gr += ov.x*a.x + ov.y*a.y + ov.z*a.z + ov.w*a.w;
        gz += ov.x*c.x + ov.y*c.y + ov.z*c.z + ov.w*c.w;
        gn += ov.x*d.x + ov.y*d.y + ov.z*d.z + ov.w*d.w;
      }
    }
    float hr = bh_r, hz = bh_z, hn_ = bh_n;
    #pragma unroll
    for (int k = 0; k < 16; ++k) {
      float hv = s_h[n][k];
      hr  += s_wh[u][k] * hv;
      hz  += s_wh[16 + u][k] * hv;
      hn_ += s_wh[32 + u][k] * hv;
    }
    float r = sigf(gr + hr);
    float z = sigf(gz + hz);
    float nn2 = tanhfast(gn + r * hn_);
    float hnew = (1.f - z) * nn2 + z * hcur;
    __syncthreads();
    s_h[n][u] = hnew;
    hcur = hnew;
    float part = hnew * fw;
    #pragma unroll
    for (int m = 8; m >= 1; m >>= 1) part += __shfl_xor(part, m);
    if (u == 0 && valid) lsnr_out[step * 1000 + n0 + n] = sigf(part + fb) * 50.f - 15.f;
    __syncthreads();
  }
  if (valid) hsnr_out[(size_t)(n0 + n) * 16 + u] = hcur;
}

// ---------------------------------------------------------------------------
// K5: xe = LN(x1 + e); m = sigmoid(LN(conv2(xe)))
// ---------------------------------------------------------------------------
__global__ __launch_bounds__(256) void k_final(
    const u16* __restrict__ x1g, const u16* __restrict__ ob,
    const float* __restrict__ lng, const float* __restrict__ lnb,
    const float* __restrict__ c2w, const float* __restrict__ c2b,
    const float* __restrict__ g2, const float* __restrict__ be2,
    float* __restrict__ m_out)
{
  const int bt = blockIdx.x, tid = threadIdx.x;
  __shared__ float s_xe[8][34];
  __shared__ float s_y[32];
  const int c = tid >> 5, f = tid & 31;
  float v = bf2f(x1g[(size_t)bt * 256 + tid]) + bf2f(ob[(size_t)bt * 256 + tid]);
  float s = v, ss = v * v;
  #pragma unroll
  for (int m = 16; m >= 1; m >>= 1) { s += __shfl_xor(s, m); ss += __shfl_xor(ss, m); }
  float mu = s * (1.f/32.f), rs = rsqrtf(ss * (1.f/32.f) - mu * mu + 1e-5f);
  s_xe[c][1 + f] = (v - mu) * rs * lng[f] + lnb[f];
  if (tid < 8) { s_xe[tid][0] = 0.f; s_xe[tid][33] = 0.f; }
  __syncthreads();
  if (tid < 32) {
    float a = c2b[0];
    #pragma unroll
    for (int cc = 0; cc < 8; ++cc) {
      const float* wr = c2w + cc * 3;
      a += wr[0]*s_xe[cc][tid] + wr[1]*s_xe[cc][tid+1] + wr[2]*s_xe[cc][tid+2];
    }
    s_y[tid] = a;
  }
  __syncthreads();
  if (tid < 32) {
    float y = s_y[tid];
    float s2 = y, ss2 = y * y;
    #pragma unroll
    for (int m = 16; m >= 1; m >>= 1) { s2 += __shfl_xor(s2, m); ss2 += __shfl_xor(ss2, m); }
    float mu2 = s2 * (1.f/32.f), rs2 = rsqrtf(ss2 * (1.f/32.f) - mu2 * mu2 + 1e-5f);
    float yn = (y - mu2) * rs2 * g2[tid] + be2[tid];
    m_out[(size_t)bt * 32 + tid] = sigf(yn);
  }
}

// ---------------------------------------------------------------------------
extern "C" void kernel_launch(void* const* d_in, const int* in_sizes, int n_in,
                              void* d_out, int out_size, void* d_ws, size_t ws_size,
                              hipStream_t stream)
{
  const float* input = (const float*)d_in[0];
  const float* w0    = (const float*)d_in[1];
  const float* b0    = (const float*)d_in[2];
  const float* ln0g  = (const float*)d_in[3];
  const float* ln0b  = (const float*)d_in[4];
  const float* w1    = (const float*)d_in[5];
  const float* b1    = (const float*)d_in[6];
  const float* ln1g  = (const float*)d_in[7];
  const float* ln1b  = (const float*)d_in[8];
  const float* qw    = (const float*)d_in[9];
  const float* qb    = (const float*)d_in[10];
  const float* kw    = (const float*)d_in[11];
  const float* kb    = (const float*)d_in[12];
  const float* vw    = (const float*)d_in[13];
  const float* vb    = (const float*)d_in[14];
  const float* gwih  = (const float*)d_in[15];
  const float* gwhh  = (const float*)d_in[16];
  const float* gbih  = (const float*)d_in[17];
  const float* gbhh  = (const float*)d_in[18];
  const float* lng   = (const float*)d_in[19];
  const float* lnb   = (const float*)d_in[20];
  const float* swih  = (const float*)d_in[21];
  const float* swhh  = (const float*)d_in[22];
  const float* sbih  = (const float*)d_in[23];
  const float* sbhh  = (const float*)d_in[24];
  const float* fcw   = (const float*)d_in[25];
  const float* fcb   = (const float*)d_in[26];
  const float* c2w   = (const float*)d_in[27];
  const float* c2b   = (const float*)d_in[28];
  const float* ln2g  = (const float*)d_in[29];
  const float* ln2b  = (const float*)d_in[30];
  (void)in_sizes; (void)n_in; (void)out_size;

  char* ws = (char*)d_ws;
  size_t off = 0;
  auto take = [&](size_t bytes) -> void* {
    void* p = ws + off;
    off += (bytes + 255) & ~(size_t)255;
    return p;
  };
  u16* x1g = (u16*)take((size_t)32000 * 256 * 2);
  u16* ob  = (u16*)take((size_t)32000 * 256 * 2);

  // Adaptive sizing: GB = batch elements per GRU group; CH = frontend/gemm
  // chunk rows. Pick largest GB whose gih+gi staging fits in remaining ws.
  const size_t fixedoff = off;
  int GB = 32;
  while (GB > 1) {
    int ch = 6400; if (ch > GB * 1000) ch = ((GB * 1000 + 63) / 64) * 64;
    size_t need = fixedoff + ((size_t)GB * 1000 * 768 * 2 + 256)
                           + ((size_t)ch * 2048 * 2 + 256);
    if (need <= ws_size) break;
    GB >>= 1;
  }
  int CH = 6400; if (CH > GB * 1000) CH = ((GB * 1000 + 63) / 64) * 64;
  u16* gih = (u16*)take((size_t)GB * 1000 * 768 * 2);
  u16* gi  = (u16*)take((size_t)CH * 2048 * 2);

  float* out      = (float*)d_out;
  float* m_out    = out;                 // [32,1,1000,32] = 1,024,000
  float* lsnr_out = out + 1024000;       // [32,1000,1]    =    32,000
  float* hatt_out = out + 1056000;       // [1,32,256]     =     8,192
  float* hsnr_out = out + 1064192;       // [1,1000,16]    =    16,000

  const int NG = 32 / GB;
  for (int g = 0; g < NG; ++g) {
    const int row0 = g * GB * 1000, rows = GB * 1000;
    for (int c0 = 0; c0 < rows; c0 += CH) {
      const int Mc = (rows - c0 < CH) ? (rows - c0) : CH;
      k_frontend<<<Mc, 256, 0, stream>>>(input, w0, b0, ln0g, ln0b, w1, b1,
                                         ln1g, ln1b, qw, qb, kw, kb, vw, vb,
                                         row0 + c0, x1g, gi);
      dim3 gg((Mc + 63) / 64, 12);
      k_gemm_bias<<<gg, 256, 0, stream>>>(gi, gwih, gbih, gih + (size_t)c0 * 768, Mc);
    }
    k_gru_batch<<<GB, 1024, 0, stream>>>(gih, gwhh, gbhh, ob, hatt_out, g * GB);
  }
  k_gru_snr<<<64, 256, 0, stream>>>(ob, swih, swhh, sbih, sbhh, fcw, fcb,
                                    lsnr_out, hsnr_out);
  k_final<<<32000, 256, 0, stream>>>(x1g, ob, lng, lnb, c2w, c2b, ln2g, ln2b, m_out);
}

// Round 3
// 14078.078 us; speedup vs baseline: 1.7045x; 1.7045x over previous
//
#include <hip/hip_runtime.h>

// ErbStage: conv0+LN+ReLU -> conv1+LN+ReLU -> spectral attention -> GRU(T=1000)
//           -> GRU(B=32 scan) + lsnr -> LN/conv2/LN/sigmoid mask.
//
// R2: k_gru_batch rewritten — whh register-stationary (192 VGPR/thread),
//     skewed LDS h layout (stride 264 -> conflict-free ds_read_b128).

typedef unsigned short u16;
typedef u16 u16x8 __attribute__((ext_vector_type(8)));

__device__ __forceinline__ float sigf(float x) { return 1.f / (1.f + __expf(-x)); }
__device__ __forceinline__ float tanhfast(float x) { return 2.f / (1.f + __expf(-2.f * x)) - 1.f; }
__device__ __forceinline__ float bf2f(u16 s) { union { unsigned u; float f; } x; x.u = ((unsigned)s) << 16; return x.f; }
__device__ __forceinline__ u16 f2bf(float f) {
  union { float f; unsigned u; } x; x.f = f;
  unsigned r = x.u + 0x7fffu + ((x.u >> 16) & 1u);
  return (u16)(r >> 16);
}

// ---------------------------------------------------------------------------
// K1: fused frontend per (b,t): conv0+LN+ReLU -> conv1+LN+ReLU (store x1 bf16)
//     -> q/k/v 1x3 convs -> QK^T/8 -> joint softmax(1024) -> att*V -> gi (bf16)
// ---------------------------------------------------------------------------
__global__ __launch_bounds__(256) void k_frontend(
    const float* __restrict__ in,
    const float* __restrict__ w0c, const float* __restrict__ b0c,
    const float* __restrict__ g0, const float* __restrict__ be0,
    const float* __restrict__ w1c, const float* __restrict__ b1c,
    const float* __restrict__ g1, const float* __restrict__ be1,
    const float* __restrict__ qw, const float* __restrict__ qb,
    const float* __restrict__ kw, const float* __restrict__ kb,
    const float* __restrict__ vw, const float* __restrict__ vb,
    int bt0, u16* __restrict__ x1g, u16* __restrict__ gi)
{
  const int bt = bt0 + blockIdx.x, tid = threadIdx.x;
  __shared__ float s_in[34];
  __shared__ float s_x0[16][34];
  __shared__ float s_x1[8][34];
  __shared__ float s_q[64][32];
  __shared__ float s_k[64][32];
  __shared__ float s_v[32][64];
  __shared__ float s_sc[32][32];
  __shared__ float s_red[8];
  __shared__ float s_mu[16], s_rs[16];

  if (tid < 32) s_in[1 + tid] = in[(size_t)bt * 32 + tid];
  if (tid == 0) { s_in[0] = 0.f; s_in[33] = 0.f; }
  __syncthreads();

  // conv0 (1->16)
  #pragma unroll
  for (int i = 0; i < 2; ++i) {
    int o = tid + i * 256, c = o >> 5, f = o & 31;
    float a = b0c[c] + w0c[c*3]*s_in[f] + w0c[c*3+1]*s_in[f+1] + w0c[c*3+2]*s_in[f+2];
    s_x0[c][1 + f] = a;
  }
  __syncthreads();
  // ln0 stats: 16 channels x 16 threads
  {
    int c = tid >> 4, i = tid & 15;
    float a = s_x0[c][1 + i], b = s_x0[c][17 + i];
    float s = a + b, ss = a * a + b * b;
    #pragma unroll
    for (int m = 8; m >= 1; m >>= 1) { s += __shfl_xor(s, m); ss += __shfl_xor(ss, m); }
    if (i == 0) { float mu = s * (1.f/32.f); s_mu[c] = mu; s_rs[c] = rsqrtf(ss * (1.f/32.f) - mu*mu + 1e-5f); }
  }
  __syncthreads();
  #pragma unroll
  for (int i = 0; i < 2; ++i) {
    int o = tid + i * 256, c = o >> 5, f = o & 31;
    float v = (s_x0[c][1 + f] - s_mu[c]) * s_rs[c] * g0[f] + be0[f];
    s_x0[c][1 + f] = fmaxf(v, 0.f);
  }
  if (tid < 16) { s_x0[tid][0] = 0.f; s_x0[tid][33] = 0.f; }
  __syncthreads();

  // conv1 (16->8) + ln1 + relu; one thread per (c1,f)
  {
    int c = tid >> 5, f = tid & 31;
    float a = b1c[c];
    #pragma unroll
    for (int cc = 0; cc < 16; ++cc) {
      const float* wr = w1c + (c * 16 + cc) * 3;
      a += wr[0]*s_x0[cc][f] + wr[1]*s_x0[cc][f+1] + wr[2]*s_x0[cc][f+2];
    }
    float s = a, ss = a * a;
    #pragma unroll
    for (int m = 16; m >= 1; m >>= 1) { s += __shfl_xor(s, m); ss += __shfl_xor(ss, m); }
    float mu = s * (1.f/32.f), rs = rsqrtf(ss * (1.f/32.f) - mu*mu + 1e-5f);
    float v = fmaxf((a - mu) * rs * g1[f] + be1[f], 0.f);
    s_x1[c][1 + f] = v;
    x1g[(size_t)bt * 256 + tid] = f2bf(v);
  }
  if (tid < 8) { s_x1[tid][0] = 0.f; s_x1[tid][33] = 0.f; }
  __syncthreads();

  // q/k/v convs (8->64 each). thread: h = tid>>2, fg = tid&3, 8 f's each
  {
    int h = tid >> 2, fg = tid & 3;
    float aq[8], ak[8], av[8];
    float qbv = qb[h], kbv = kb[h], vbv = vb[h];
    #pragma unroll
    for (int i = 0; i < 8; ++i) { aq[i] = qbv; ak[i] = kbv; av[i] = vbv; }
    #pragma unroll
    for (int c = 0; c < 8; ++c) {
      const float* qr = qw + (h * 8 + c) * 3;
      const float* kr = kw + (h * 8 + c) * 3;
      const float* vr = vw + (h * 8 + c) * 3;
      float q0 = qr[0], q1 = qr[1], q2 = qr[2];
      float k0 = kr[0], k1 = kr[1], k2 = kr[2];
      float v0 = vr[0], v1 = vr[1], v2 = vr[2];
      #pragma unroll
      for (int i = 0; i < 8; ++i) {
        int f = fg + i * 4;
        float xa = s_x1[c][f], xb = s_x1[c][f+1], xc = s_x1[c][f+2];
        aq[i] += q0*xa + q1*xb + q2*xc;
        ak[i] += k0*xa + k1*xb + k2*xc;
        av[i] += v0*xa + v1*xb + v2*xc;
      }
    }
    #pragma unroll
    for (int i = 0; i < 8; ++i) {
      int f = fg + i * 4;
      s_q[h][f] = aq[i];
      s_k[h][f] = ak[i];
      s_v[f][h] = av[i];
    }
  }
  __syncthreads();

  // scores w[f][g] = sum_h q[h][f]*k[h][g] / 8
  float sc[4];
  #pragma unroll
  for (int i = 0; i < 4; ++i) {
    int o = tid + i * 256, f = o >> 5, g = o & 31;
    float a = 0.f;
    #pragma unroll 8
    for (int h = 0; h < 64; ++h) a += s_q[h][f] * s_k[h][g];
    sc[i] = a * 0.125f;
  }
  // joint softmax over all 1024
  float mx = fmaxf(fmaxf(sc[0], sc[1]), fmaxf(sc[2], sc[3]));
  #pragma unroll
  for (int m = 32; m >= 1; m >>= 1) mx = fmaxf(mx, __shfl_xor(mx, m));
  if ((tid & 63) == 0) s_red[tid >> 6] = mx;
  __syncthreads();
  mx = fmaxf(fmaxf(s_red[0], s_red[1]), fmaxf(s_red[2], s_red[3]));
  float sm = 0.f;
  #pragma unroll
  for (int i = 0; i < 4; ++i) { sc[i] = __expf(sc[i] - mx); sm += sc[i]; }
  #pragma unroll
  for (int m = 32; m >= 1; m >>= 1) sm += __shfl_xor(sm, m);
  __syncthreads();
  if ((tid & 63) == 0) s_red[4 + (tid >> 6)] = sm;
  __syncthreads();
  float inv = 1.f / (s_red[4] + s_red[5] + s_red[6] + s_red[7]);
  #pragma unroll
  for (int i = 0; i < 4; ++i) {
    int o = tid + i * 256, f = o >> 5, g = o & 31;
    s_sc[f][g] = sc[i] * inv;
  }
  __syncthreads();

  // att[f][h] = sum_g w[f][g]*v[g][h] ; gi row local to chunk
  u16* gir = gi + (size_t)blockIdx.x * 2048;
  #pragma unroll
  for (int i = 0; i < 8; ++i) {
    int o = tid + i * 256, f = o >> 6, h = o & 63;
    float a = 0.f;
    #pragma unroll 8
    for (int g = 0; g < 32; ++g) a += s_sc[f][g] * s_v[g][h];
    gir[o] = f2bf(a);
  }
}

// ---------------------------------------------------------------------------
// K2: C[M,768](bf16) = A[M,2048](bf16) @ W[768,2048]^T(f32) + bias
// ---------------------------------------------------------------------------
__global__ __launch_bounds__(256) void k_gemm_bias(
    const u16* __restrict__ A, const float* __restrict__ W,
    const float* __restrict__ bias, u16* __restrict__ C, int M)
{
  const int K = 2048, N = 768;
  __shared__ float As[16][68];   // [k][row]
  __shared__ float Ws[16][68];
  const int tid = threadIdx.x;
  const int m0 = blockIdx.x * 64, n0 = blockIdx.y * 64;
  const int ty = tid >> 4, tx = tid & 15;
  const int lr = tid >> 2, lk = (tid & 3) * 4;
  float acc[4][4] = {};
  for (int k0 = 0; k0 < K; k0 += 16) {
    {
      int ar = m0 + lr;
      ushort4 av = make_ushort4(0, 0, 0, 0);
      if (ar < M) av = *(const ushort4*)(A + (size_t)ar * K + k0 + lk);
      As[lk + 0][lr] = bf2f(av.x);
      As[lk + 1][lr] = bf2f(av.y);
      As[lk + 2][lr] = bf2f(av.z);
      As[lk + 3][lr] = bf2f(av.w);
      float4 wv = *(const float4*)(W + (size_t)(n0 + lr) * K + k0 + lk);
      Ws[lk + 0][lr] = wv.x;
      Ws[lk + 1][lr] = wv.y;
      Ws[lk + 2][lr] = wv.z;
      Ws[lk + 3][lr] = wv.w;
    }
    __syncthreads();
    #pragma unroll
    for (int k = 0; k < 16; ++k) {
      float4 a = *(const float4*)&As[k][ty * 4];
      float4 b = *(const float4*)&Ws[k][tx * 4];
      float ar[4] = {a.x, a.y, a.z, a.w}, br[4] = {b.x, b.y, b.z, b.w};
      #pragma unroll
      for (int i = 0; i < 4; ++i)
        #pragma unroll
        for (int j = 0; j < 4; ++j) acc[i][j] += ar[i] * br[j];
    }
    __syncthreads();
  }
  #pragma unroll
  for (int i = 0; i < 4; ++i) {
    int m = m0 + ty * 4 + i;
    int n = n0 + tx * 4;
    if (m < M) {
      ushort4 o4;
      o4.x = f2bf(acc[i][0] + bias[n + 0]);
      o4.y = f2bf(acc[i][1] + bias[n + 1]);
      o4.z = f2bf(acc[i][2] + bias[n + 2]);
      o4.w = f2bf(acc[i][3] + bias[n + 3]);
      *(ushort4*)&C[(size_t)m * N + n] = o4;
    }
  }
}

// ---------------------------------------------------------------------------
// K3: main GRU over T=1000. One 1024-thread block per batch element, no grid
//     sync. whh held REGISTER-STATIONARY: thread (u=tid>>2, part=tid&3) owns
//     the 64-wide k-slice of rows {u, 256+u, 512+u} = 48 float4 = 192 VGPR.
//     h double-buffered in LDS with skewed chunk stride 264 floats
//     (264%32==8 -> the 4 parts' ds_read_b128 hit disjoint bank sets).
// ---------------------------------------------------------------------------
#define HSKEW 264
__global__ __launch_bounds__(1024, 1) void k_gru_batch(
    const u16* __restrict__ gih, const float* __restrict__ whh,
    const float* __restrict__ bhh, u16* __restrict__ ob,
    float* __restrict__ hatt, int b0)
{
  __shared__ float s_h[2][4 * HSKEW];
  const int tid = threadIdx.x;
  const int u = tid >> 2, part = tid & 3;
  const int bl = blockIdx.x;     // local b within this group
  const int b = b0 + bl;         // global b

  // one-time weight load into registers (scattered; ~25us total, amortized)
  float4 wr_[16], wz_[16], wn_[16];
  {
    const float4* wr4 = (const float4*)(whh + (size_t)(      u) * 256 + part * 64);
    const float4* wz4 = (const float4*)(whh + (size_t)(256 + u) * 256 + part * 64);
    const float4* wn4 = (const float4*)(whh + (size_t)(512 + u) * 256 + part * 64);
    #pragma unroll
    for (int k4 = 0; k4 < 16; ++k4) { wr_[k4] = wr4[k4]; wz_[k4] = wz4[k4]; wn_[k4] = wn4[k4]; }
  }
  float bh_r = 0.f, bh_z = 0.f, bh_n = 0.f;
  if (part == 0) { bh_r = bhh[u]; bh_z = bhh[256 + u]; bh_n = bhh[512 + u]; }
  if (tid < 256) s_h[0][(tid >> 6) * HSKEW + (tid & 63)] = 0.f;
  __syncthreads();

  const int hoff = (u >> 6) * HSKEW + (u & 63);   // where h[u] lives
  int cur = 0;
  for (int t = 0; t < 1000; ++t) {
    const float4* h4 = (const float4*)(&s_h[cur][part * HSKEW]);
    float pr = 0.f, pz = 0.f, pn = 0.f;
    #pragma unroll
    for (int k4 = 0; k4 < 16; ++k4) {
      float4 hv = h4[k4];
      pr += hv.x*wr_[k4].x + hv.y*wr_[k4].y + hv.z*wr_[k4].z + hv.w*wr_[k4].w;
      pz += hv.x*wz_[k4].x + hv.y*wz_[k4].y + hv.z*wz_[k4].z + hv.w*wz_[k4].w;
      pn += hv.x*wn_[k4].x + hv.y*wn_[k4].y + hv.z*wn_[k4].z + hv.w*wn_[k4].w;
    }
    pr += __shfl_xor(pr, 1); pr += __shfl_xor(pr, 2);
    pz += __shfl_xor(pz, 1); pz += __shfl_xor(pz, 2);
    pn += __shfl_xor(pn, 1); pn += __shfl_xor(pn, 2);
    if (part == 0) {
      const u16* gr_ = gih + ((size_t)bl * 1000 + t) * 768;
      float hold = s_h[cur][hoff];
      float r = sigf(bf2f(gr_[u]) + pr + bh_r);
      float z = sigf(bf2f(gr_[256 + u]) + pz + bh_z);
      float n = tanhfast(bf2f(gr_[512 + u]) + r * (pn + bh_n));
      float hnew = (1.f - z) * n + z * hold;
      s_h[cur ^ 1][hoff] = hnew;
      ob[((size_t)b * 1000 + t) * 256 + u] = f2bf(hnew);
      if (t == 999) hatt[b * 256 + u] = hnew;
    }
    __syncthreads();
    cur ^= 1;
  }
}

// ---------------------------------------------------------------------------
// K4: snr GRU scans over B=32 steps; batch dim = T (independent per t).
//     64 WGs x 16 t-rows, grus_wih LDS-stationary, lsnr fused.
// ---------------------------------------------------------------------------
__global__ __launch_bounds__(256) void k_gru_snr(
    const u16* __restrict__ ob, const float* __restrict__ wih,
    const float* __restrict__ whh, const float* __restrict__ bih,
    const float* __restrict__ bhh, const float* __restrict__ fcw,
    const float* __restrict__ fcb,
    float* __restrict__ lsnr_out, float* __restrict__ hsnr_out)
{
  __shared__ float s_wi[48][260];
  __shared__ float s_wh[48][20];
  __shared__ float s_o[16][260];
  __shared__ float s_h[16][20];
  const int tid = threadIdx.x, wg = blockIdx.x;
  const int n0 = wg * 16;
  for (int i = tid; i < 48 * 256; i += 256) s_wi[i >> 8][i & 255] = wih[i];
  for (int i = tid; i < 768; i += 256) s_wh[i >> 4][i & 15] = whh[i];
  const int n = tid >> 4, u = tid & 15;
  const bool valid = (n0 + n) < 1000;
  s_h[n][u] = 0.f;
  float hcur = 0.f;
  const float bi_r = bih[u], bi_z = bih[16 + u], bi_n = bih[32 + u];
  const float bh_r = bhh[u], bh_z = bhh[16 + u], bh_n = bhh[32 + u];
  const float fw = fcw[u], fb = fcb[0];
  __syncthreads();
  for (int step = 0; step < 32; ++step) {
    for (int i = tid; i < 512; i += 256) {
      int nn = i >> 5, c8 = (i & 31) * 8;
      int row = n0 + nn;
      if (row < 1000) {
        u16x8 v = *(const u16x8*)(ob + ((size_t)step * 1000 + row) * 256 + c8);
        #pragma unroll
        for (int j = 0; j < 8; ++j) s_o[nn][c8 + j] = bf2f(v[j]);
      } else {
        #pragma unroll
        for (int j = 0; j < 8; ++j) s_o[nn][c8 + j] = 0.f;
      }
    }
    __syncthreads();
    float gr = bi_r, gz = bi_z, gn = bi_n;
    {
      const float4* o4 = (const float4*)&s_o[n][0];
      const float4* wr = (const float4*)&s_wi[u][0];
      const float4* wz = (const float4*)&s_wi[16 + u][0];
      const float4* wn = (const float4*)&s_wi[32 + u][0];
      #pragma unroll 4
      for (int k4 = 0; k4 < 64; ++k4) {
        float4 ov = o4[k4];
        float4 a = wr[k4], c = wz[k4], d = wn[k4];
        gr += ov.x*a.x + ov.y*a.y + ov.z*a.z + ov.w*a.w;
        gz += ov.x*c.x + ov.y*c.y + ov.z*c.z + ov.w*c.w;
        gn += ov.x*d.x + ov.y*d.y + ov.z*d.z + ov.w*d.w;
      }
    }
    float hr = bh_r, hz = bh_z, hn_ = bh_n;
    #pragma unroll
    for (int k = 0; k < 16; ++k) {
      float hv = s_h[n][k];
      hr  += s_wh[u][k] * hv;
      hz  += s_wh[16 + u][k] * hv;
      hn_ += s_wh[32 + u][k] * hv;
    }
    float r = sigf(gr + hr);
    float z = sigf(gz + hz);
    float nn2 = tanhfast(gn + r * hn_);
    float hnew = (1.f - z) * nn2 + z * hcur;
    __syncthreads();
    s_h[n][u] = hnew;
    hcur = hnew;
    float part = hnew * fw;
    #pragma unroll
    for (int m = 8; m >= 1; m >>= 1) part += __shfl_xor(part, m);
    if (u == 0 && valid) lsnr_out[step * 1000 + n0 + n] = sigf(part + fb) * 50.f - 15.f;
    __syncthreads();
  }
  if (valid) hsnr_out[(size_t)(n0 + n) * 16 + u] = hcur;
}

// ---------------------------------------------------------------------------
// K5: xe = LN(x1 + e); m = sigmoid(LN(conv2(xe)))
// ---------------------------------------------------------------------------
__global__ __launch_bounds__(256) void k_final(
    const u16* __restrict__ x1g, const u16* __restrict__ ob,
    const float* __restrict__ lng, const float* __restrict__ lnb,
    const float* __restrict__ c2w, const float* __restrict__ c2b,
    const float* __restrict__ g2, const float* __restrict__ be2,
    float* __restrict__ m_out)
{
  const int bt = blockIdx.x, tid = threadIdx.x;
  __shared__ float s_xe[8][34];
  __shared__ float s_y[32];
  const int c = tid >> 5, f = tid & 31;
  float v = bf2f(x1g[(size_t)bt * 256 + tid]) + bf2f(ob[(size_t)bt * 256 + tid]);
  float s = v, ss = v * v;
  #pragma unroll
  for (int m = 16; m >= 1; m >>= 1) { s += __shfl_xor(s, m); ss += __shfl_xor(ss, m); }
  float mu = s * (1.f/32.f), rs = rsqrtf(ss * (1.f/32.f) - mu * mu + 1e-5f);
  s_xe[c][1 + f] = (v - mu) * rs * lng[f] + lnb[f];
  if (tid < 8) { s_xe[tid][0] = 0.f; s_xe[tid][33] = 0.f; }
  __syncthreads();
  if (tid < 32) {
    float a = c2b[0];
    #pragma unroll
    for (int cc = 0; cc < 8; ++cc) {
      const float* wr = c2w + cc * 3;
      a += wr[0]*s_xe[cc][tid] + wr[1]*s_xe[cc][tid+1] + wr[2]*s_xe[cc][tid+2];
    }
    s_y[tid] = a;
  }
  __syncthreads();
  if (tid < 32) {
    float y = s_y[tid];
    float s2 = y, ss2 = y * y;
    #pragma unroll
    for (int m = 16; m >= 1; m >>= 1) { s2 += __shfl_xor(s2, m); ss2 += __shfl_xor(ss2, m); }
    float mu2 = s2 * (1.f/32.f), rs2 = rsqrtf(ss2 * (1.f/32.f) - mu2 * mu2 + 1e-5f);
    float yn = (y - mu2) * rs2 * g2[tid] + be2[tid];
    m_out[(size_t)bt * 32 + tid] = sigf(yn);
  }
}

// ---------------------------------------------------------------------------
extern "C" void kernel_launch(void* const* d_in, const int* in_sizes, int n_in,
                              void* d_out, int out_size, void* d_ws, size_t ws_size,
                              hipStream_t stream)
{
  const float* input = (const float*)d_in[0];
  const float* w0    = (const float*)d_in[1];
  const float* b0    = (const float*)d_in[2];
  const float* ln0g  = (const float*)d_in[3];
  const float* ln0b  = (const float*)d_in[4];
  const float* w1    = (const float*)d_in[5];
  const float* b1    = (const float*)d_in[6];
  const float* ln1g  = (const float*)d_in[7];
  const float* ln1b  = (const float*)d_in[8];
  const float* qw    = (const float*)d_in[9];
  const float* qb    = (const float*)d_in[10];
  const float* kw    = (const float*)d_in[11];
  const float* kb    = (const float*)d_in[12];
  const float* vw    = (const float*)d_in[13];
  const float* vb    = (const float*)d_in[14];
  const float* gwih  = (const float*)d_in[15];
  const float* gwhh  = (const float*)d_in[16];
  const float* gbih  = (const float*)d_in[17];
  const float* gbhh  = (const float*)d_in[18];
  const float* lng   = (const float*)d_in[19];
  const float* lnb   = (const float*)d_in[20];
  const float* swih  = (const float*)d_in[21];
  const float* swhh  = (const float*)d_in[22];
  const float* sbih  = (const float*)d_in[23];
  const float* sbhh  = (const float*)d_in[24];
  const float* fcw   = (const float*)d_in[25];
  const float* fcb   = (const float*)d_in[26];
  const float* c2w   = (const float*)d_in[27];
  const float* c2b   = (const float*)d_in[28];
  const float* ln2g  = (const float*)d_in[29];
  const float* ln2b  = (const float*)d_in[30];
  (void)in_sizes; (void)n_in; (void)out_size;

  char* ws = (char*)d_ws;
  size_t off = 0;
  auto take = [&](size_t bytes) -> void* {
    void* p = ws + off;
    off += (bytes + 255) & ~(size_t)255;
    return p;
  };
  u16* x1g = (u16*)take((size_t)32000 * 256 * 2);
  u16* ob  = (u16*)take((size_t)32000 * 256 * 2);

  // Adaptive sizing: GB = batch elements per GRU group; CH = frontend/gemm
  // chunk rows. Pick largest GB whose gih+gi staging fits in remaining ws.
  const size_t fixedoff = off;
  int GB = 32;
  while (GB > 1) {
    int ch = 6400; if (ch > GB * 1000) ch = ((GB * 1000 + 63) / 64) * 64;
    size_t need = fixedoff + ((size_t)GB * 1000 * 768 * 2 + 256)
                           + ((size_t)ch * 2048 * 2 + 256);
    if (need <= ws_size) break;
    GB >>= 1;
  }
  int CH = 6400; if (CH > GB * 1000) CH = ((GB * 1000 + 63) / 64) * 64;
  u16* gih = (u16*)take((size_t)GB * 1000 * 768 * 2);
  u16* gi  = (u16*)take((size_t)CH * 2048 * 2);

  float* out      = (float*)d_out;
  float* m_out    = out;                 // [32,1,1000,32] = 1,024,000
  float* lsnr_out = out + 1024000;       // [32,1000,1]    =    32,000
  float* hatt_out = out + 1056000;       // [1,32,256]     =     8,192
  float* hsnr_out = out + 1064192;       // [1,1000,16]    =    16,000

  const int NG = 32 / GB;
  for (int g = 0; g < NG; ++g) {
    const int row0 = g * GB * 1000, rows = GB * 1000;
    for (int c0 = 0; c0 < rows; c0 += CH) {
      const int Mc = (rows - c0 < CH) ? (rows - c0) : CH;
      k_frontend<<<Mc, 256, 0, stream>>>(input, w0, b0, ln0g, ln0b, w1, b1,
                                         ln1g, ln1b, qw, qb, kw, kb, vw, vb,
                                         row0 + c0, x1g, gi);
      dim3 gg((Mc + 63) / 64, 12);
      k_gemm_bias<<<gg, 256, 0, stream>>>(gi, gwih, gbih, gih + (size_t)c0 * 768, Mc);
    }
    k_gru_batch<<<GB, 1024, 0, stream>>>(gih, gwhh, gbhh, ob, hatt_out, g * GB);
  }
  k_gru_snr<<<64, 256, 0, stream>>>(ob, swih, swhh, sbih, sbhh, fcw, fcb,
                                    lsnr_out, hsnr_out);
  k_final<<<32000, 256, 0, stream>>>(x1g, ob, lng, lnb, c2w, c2b, ln2g, ln2b, m_out);
}

// Round 5
// 3707.763 us; speedup vs baseline: 6.4719x; 3.7969x over previous
//
#include <hip/hip_runtime.h>

// ErbStage: conv0+LN+ReLU -> conv1+LN+ReLU -> spectral attention -> GRU(T=1000)
//           -> GRU(B=32 scan) + lsnr -> LN/conv2/LN/sigmoid mask.
//
// R4: fix compile — cvt_pkrtz returns __fp16x2; bit-cast into _Float16x2 (h2t)
//     via pk() wrapper. Logic identical to R3:
//     k_gru_batch: whh packed-f16 register-stationary (192 VGPR/thread,
//     512-thread block, launch_bounds(512,2) -> 256 cap), v_dot2_f32_f16
//     inner product, h packed-f16 in LDS (double-buffered).

typedef unsigned short u16;
typedef u16 u16x8 __attribute__((ext_vector_type(8)));
typedef _Float16 h2t __attribute__((ext_vector_type(2)));

__device__ __forceinline__ float sigf(float x) { return 1.f / (1.f + __expf(-x)); }
__device__ __forceinline__ float tanhfast(float x) { return 2.f / (1.f + __expf(-2.f * x)) - 1.f; }
__device__ __forceinline__ float bf2f(u16 s) { union { unsigned u; float f; } x; x.u = ((unsigned)s) << 16; return x.f; }
__device__ __forceinline__ u16 f2bf(float f) {
  union { float f; unsigned u; } x; x.f = f;
  unsigned r = x.u + 0x7fffu + ((x.u >> 16) & 1u);
  return (u16)(r >> 16);
}
__device__ __forceinline__ h2t pk(float a, float b) {
  auto v = __builtin_amdgcn_cvt_pkrtz(a, b);      // __fp16 ext_vector(2)
  union { decltype(v) i; h2t o; } u; u.i = v; return u.o;
}

// ---------------------------------------------------------------------------
// K1: fused frontend per (b,t): conv0+LN+ReLU -> conv1+LN+ReLU (store x1 bf16)
//     -> q/k/v 1x3 convs -> QK^T/8 -> joint softmax(1024) -> att*V -> gi (bf16)
// ---------------------------------------------------------------------------
__global__ __launch_bounds__(256) void k_frontend(
    const float* __restrict__ in,
    const float* __restrict__ w0c, const float* __restrict__ b0c,
    const float* __restrict__ g0, const float* __restrict__ be0,
    const float* __restrict__ w1c, const float* __restrict__ b1c,
    const float* __restrict__ g1, const float* __restrict__ be1,
    const float* __restrict__ qw, const float* __restrict__ qb,
    const float* __restrict__ kw, const float* __restrict__ kb,
    const float* __restrict__ vw, const float* __restrict__ vb,
    int bt0, u16* __restrict__ x1g, u16* __restrict__ gi)
{
  const int bt = bt0 + blockIdx.x, tid = threadIdx.x;
  __shared__ float s_in[34];
  __shared__ float s_x0[16][34];
  __shared__ float s_x1[8][34];
  __shared__ float s_q[64][32];
  __shared__ float s_k[64][32];
  __shared__ float s_v[32][64];
  __shared__ float s_sc[32][32];
  __shared__ float s_red[8];
  __shared__ float s_mu[16], s_rs[16];

  if (tid < 32) s_in[1 + tid] = in[(size_t)bt * 32 + tid];
  if (tid == 0) { s_in[0] = 0.f; s_in[33] = 0.f; }
  __syncthreads();

  // conv0 (1->16)
  #pragma unroll
  for (int i = 0; i < 2; ++i) {
    int o = tid + i * 256, c = o >> 5, f = o & 31;
    float a = b0c[c] + w0c[c*3]*s_in[f] + w0c[c*3+1]*s_in[f+1] + w0c[c*3+2]*s_in[f+2];
    s_x0[c][1 + f] = a;
  }
  __syncthreads();
  // ln0 stats: 16 channels x 16 threads
  {
    int c = tid >> 4, i = tid & 15;
    float a = s_x0[c][1 + i], b = s_x0[c][17 + i];
    float s = a + b, ss = a * a + b * b;
    #pragma unroll
    for (int m = 8; m >= 1; m >>= 1) { s += __shfl_xor(s, m); ss += __shfl_xor(ss, m); }
    if (i == 0) { float mu = s * (1.f/32.f); s_mu[c] = mu; s_rs[c] = rsqrtf(ss * (1.f/32.f) - mu*mu + 1e-5f); }
  }
  __syncthreads();
  #pragma unroll
  for (int i = 0; i < 2; ++i) {
    int o = tid + i * 256, c = o >> 5, f = o & 31;
    float v = (s_x0[c][1 + f] - s_mu[c]) * s_rs[c] * g0[f] + be0[f];
    s_x0[c][1 + f] = fmaxf(v, 0.f);
  }
  if (tid < 16) { s_x0[tid][0] = 0.f; s_x0[tid][33] = 0.f; }
  __syncthreads();

  // conv1 (16->8) + ln1 + relu; one thread per (c1,f)
  {
    int c = tid >> 5, f = tid & 31;
    float a = b1c[c];
    #pragma unroll
    for (int cc = 0; cc < 16; ++cc) {
      const float* wr = w1c + (c * 16 + cc) * 3;
      a += wr[0]*s_x0[cc][f] + wr[1]*s_x0[cc][f+1] + wr[2]*s_x0[cc][f+2];
    }
    float s = a, ss = a * a;
    #pragma unroll
    for (int m = 16; m >= 1; m >>= 1) { s += __shfl_xor(s, m); ss += __shfl_xor(ss, m); }
    float mu = s * (1.f/32.f), rs = rsqrtf(ss * (1.f/32.f) - mu*mu + 1e-5f);
    float v = fmaxf((a - mu) * rs * g1[f] + be1[f], 0.f);
    s_x1[c][1 + f] = v;
    x1g[(size_t)bt * 256 + tid] = f2bf(v);
  }
  if (tid < 8) { s_x1[tid][0] = 0.f; s_x1[tid][33] = 0.f; }
  __syncthreads();

  // q/k/v convs (8->64 each). thread: h = tid>>2, fg = tid&3, 8 f's each
  {
    int h = tid >> 2, fg = tid & 3;
    float aq[8], ak[8], av[8];
    float qbv = qb[h], kbv = kb[h], vbv = vb[h];
    #pragma unroll
    for (int i = 0; i < 8; ++i) { aq[i] = qbv; ak[i] = kbv; av[i] = vbv; }
    #pragma unroll
    for (int c = 0; c < 8; ++c) {
      const float* qr = qw + (h * 8 + c) * 3;
      const float* kr = kw + (h * 8 + c) * 3;
      const float* vr = vw + (h * 8 + c) * 3;
      float q0 = qr[0], q1 = qr[1], q2 = qr[2];
      float k0 = kr[0], k1 = kr[1], k2 = kr[2];
      float v0 = vr[0], v1 = vr[1], v2 = vr[2];
      #pragma unroll
      for (int i = 0; i < 8; ++i) {
        int f = fg + i * 4;
        float xa = s_x1[c][f], xb = s_x1[c][f+1], xc = s_x1[c][f+2];
        aq[i] += q0*xa + q1*xb + q2*xc;
        ak[i] += k0*xa + k1*xb + k2*xc;
        av[i] += v0*xa + v1*xb + v2*xc;
      }
    }
    #pragma unroll
    for (int i = 0; i < 8; ++i) {
      int f = fg + i * 4;
      s_q[h][f] = aq[i];
      s_k[h][f] = ak[i];
      s_v[f][h] = av[i];
    }
  }
  __syncthreads();

  // scores w[f][g] = sum_h q[h][f]*k[h][g] / 8
  float sc[4];
  #pragma unroll
  for (int i = 0; i < 4; ++i) {
    int o = tid + i * 256, f = o >> 5, g = o & 31;
    float a = 0.f;
    #pragma unroll 8
    for (int h = 0; h < 64; ++h) a += s_q[h][f] * s_k[h][g];
    sc[i] = a * 0.125f;
  }
  // joint softmax over all 1024
  float mx = fmaxf(fmaxf(sc[0], sc[1]), fmaxf(sc[2], sc[3]));
  #pragma unroll
  for (int m = 32; m >= 1; m >>= 1) mx = fmaxf(mx, __shfl_xor(mx, m));
  if ((tid & 63) == 0) s_red[tid >> 6] = mx;
  __syncthreads();
  mx = fmaxf(fmaxf(s_red[0], s_red[1]), fmaxf(s_red[2], s_red[3]));
  float sm = 0.f;
  #pragma unroll
  for (int i = 0; i < 4; ++i) { sc[i] = __expf(sc[i] - mx); sm += sc[i]; }
  #pragma unroll
  for (int m = 32; m >= 1; m >>= 1) sm += __shfl_xor(sm, m);
  __syncthreads();
  if ((tid & 63) == 0) s_red[4 + (tid >> 6)] = sm;
  __syncthreads();
  float inv = 1.f / (s_red[4] + s_red[5] + s_red[6] + s_red[7]);
  #pragma unroll
  for (int i = 0; i < 4; ++i) {
    int o = tid + i * 256, f = o >> 5, g = o & 31;
    s_sc[f][g] = sc[i] * inv;
  }
  __syncthreads();

  // att[f][h] = sum_g w[f][g]*v[g][h] ; gi row local to chunk
  u16* gir = gi + (size_t)blockIdx.x * 2048;
  #pragma unroll
  for (int i = 0; i < 8; ++i) {
    int o = tid + i * 256, f = o >> 6, h = o & 63;
    float a = 0.f;
    #pragma unroll 8
    for (int g = 0; g < 32; ++g) a += s_sc[f][g] * s_v[g][h];
    gir[o] = f2bf(a);
  }
}

// ---------------------------------------------------------------------------
// K2: C[M,768](bf16) = A[M,2048](bf16) @ W[768,2048]^T(f32) + bias
// ---------------------------------------------------------------------------
__global__ __launch_bounds__(256) void k_gemm_bias(
    const u16* __restrict__ A, const float* __restrict__ W,
    const float* __restrict__ bias, u16* __restrict__ C, int M)
{
  const int K = 2048, N = 768;
  __shared__ float As[16][68];   // [k][row]
  __shared__ float Ws[16][68];
  const int tid = threadIdx.x;
  const int m0 = blockIdx.x * 64, n0 = blockIdx.y * 64;
  const int ty = tid >> 4, tx = tid & 15;
  const int lr = tid >> 2, lk = (tid & 3) * 4;
  float acc[4][4] = {};
  for (int k0 = 0; k0 < K; k0 += 16) {
    {
      int ar = m0 + lr;
      ushort4 av = make_ushort4(0, 0, 0, 0);
      if (ar < M) av = *(const ushort4*)(A + (size_t)ar * K + k0 + lk);
      As[lk + 0][lr] = bf2f(av.x);
      As[lk + 1][lr] = bf2f(av.y);
      As[lk + 2][lr] = bf2f(av.z);
      As[lk + 3][lr] = bf2f(av.w);
      float4 wv = *(const float4*)(W + (size_t)(n0 + lr) * K + k0 + lk);
      Ws[lk + 0][lr] = wv.x;
      Ws[lk + 1][lr] = wv.y;
      Ws[lk + 2][lr] = wv.z;
      Ws[lk + 3][lr] = wv.w;
    }
    __syncthreads();
    #pragma unroll
    for (int k = 0; k < 16; ++k) {
      float4 a = *(const float4*)&As[k][ty * 4];
      float4 b = *(const float4*)&Ws[k][tx * 4];
      float ar[4] = {a.x, a.y, a.z, a.w}, br[4] = {b.x, b.y, b.z, b.w};
      #pragma unroll
      for (int i = 0; i < 4; ++i)
        #pragma unroll
        for (int j = 0; j < 4; ++j) acc[i][j] += ar[i] * br[j];
    }
    __syncthreads();
  }
  #pragma unroll
  for (int i = 0; i < 4; ++i) {
    int m = m0 + ty * 4 + i;
    int n = n0 + tx * 4;
    if (m < M) {
      ushort4 o4;
      o4.x = f2bf(acc[i][0] + bias[n + 0]);
      o4.y = f2bf(acc[i][1] + bias[n + 1]);
      o4.z = f2bf(acc[i][2] + bias[n + 2]);
      o4.w = f2bf(acc[i][3] + bias[n + 3]);
      *(ushort4*)&C[(size_t)m * N + n] = o4;
    }
  }
}

// ---------------------------------------------------------------------------
// K3: main GRU over T=1000. One 512-thread block per batch element, no grid
//     sync. whh REGISTER-STATIONARY as packed f16: thread (u=tid>>1,
//     part=tid&1) owns the 128-wide k-slice of rows {u,256+u,512+u} =
//     3*64 half2 = 192 VGPR. launch_bounds(512,2) -> 256-VGPR cap, fits.
//     Inner product: v_dot2_f32_f16 (fdot2), 6 accumulator chains.
//     h packed f16 in LDS, double-buffered; h_prev carried in-register.
// ---------------------------------------------------------------------------
__global__ __launch_bounds__(512, 2) void k_gru_batch(
    const u16* __restrict__ gih, const float* __restrict__ whh,
    const float* __restrict__ bhh, u16* __restrict__ ob,
    float* __restrict__ hatt, int b0)
{
  __shared__ h2t s_h2[2][128];   // h packed as 128 half2 (h[2j], h[2j+1])
  const int tid = threadIdx.x;
  const int u = tid >> 1, part = tid & 1;
  const int bl = blockIdx.x;     // local b within this group
  const int b = b0 + bl;         // global b

  // one-time weight load + f32->f16 pack (786KB/block, amortized over 1000 steps)
  h2t wr_[64], wz_[64], wn_[64];
  {
    const float4* r4 = (const float4*)(whh + (size_t)(      u) * 256 + part * 128);
    const float4* z4 = (const float4*)(whh + (size_t)(256 + u) * 256 + part * 128);
    const float4* n4 = (const float4*)(whh + (size_t)(512 + u) * 256 + part * 128);
    #pragma unroll
    for (int j = 0; j < 32; ++j) {
      float4 a = r4[j];
      wr_[2*j]   = pk(a.x, a.y);
      wr_[2*j+1] = pk(a.z, a.w);
      float4 c = z4[j];
      wz_[2*j]   = pk(c.x, c.y);
      wz_[2*j+1] = pk(c.z, c.w);
      float4 d = n4[j];
      wn_[2*j]   = pk(d.x, d.y);
      wn_[2*j+1] = pk(d.z, d.w);
    }
  }
  float bh_r = 0.f, bh_z = 0.f, bh_n = 0.f;
  if (part == 0) { bh_r = bhh[u]; bh_z = bhh[256 + u]; bh_n = bhh[512 + u]; }
  if (tid < 128) s_h2[0][tid] = pk(0.f, 0.f);
  __syncthreads();

  float hprev = 0.f;             // part0: running h[u]
  int cur = 0;
  union H4 { uint4 u4; h2t h[4]; };
  for (int t = 0; t < 1000; ++t) {
    // issue gih loads early so they overlap the dot-product work
    float gi_r = 0.f, gi_z = 0.f, gi_n = 0.f;
    if (part == 0) {
      const u16* gr_ = gih + ((size_t)bl * 1000 + t) * 768;
      gi_r = bf2f(gr_[u]); gi_z = bf2f(gr_[256 + u]); gi_n = bf2f(gr_[512 + u]);
    }
    const uint4* hp = (const uint4*)&s_h2[cur][part * 64];
    float pr0 = 0.f, pr1 = 0.f, pz0 = 0.f, pz1 = 0.f, pn0 = 0.f, pn1 = 0.f;
    #pragma unroll
    for (int k4 = 0; k4 < 16; ++k4) {
      H4 hv; hv.u4 = hp[k4];
      pr0 = __builtin_amdgcn_fdot2(hv.h[0], wr_[4*k4+0], pr0, false);
      pz0 = __builtin_amdgcn_fdot2(hv.h[0], wz_[4*k4+0], pz0, false);
      pn0 = __builtin_amdgcn_fdot2(hv.h[0], wn_[4*k4+0], pn0, false);
      pr1 = __builtin_amdgcn_fdot2(hv.h[1], wr_[4*k4+1], pr1, false);
      pz1 = __builtin_amdgcn_fdot2(hv.h[1], wz_[4*k4+1], pz1, false);
      pn1 = __builtin_amdgcn_fdot2(hv.h[1], wn_[4*k4+1], pn1, false);
      pr0 = __builtin_amdgcn_fdot2(hv.h[2], wr_[4*k4+2], pr0, false);
      pz0 = __builtin_amdgcn_fdot2(hv.h[2], wz_[4*k4+2], pz0, false);
      pn0 = __builtin_amdgcn_fdot2(hv.h[2], wn_[4*k4+2], pn0, false);
      pr1 = __builtin_amdgcn_fdot2(hv.h[3], wr_[4*k4+3], pr1, false);
      pz1 = __builtin_amdgcn_fdot2(hv.h[3], wz_[4*k4+3], pz1, false);
      pn1 = __builtin_amdgcn_fdot2(hv.h[3], wn_[4*k4+3], pn1, false);
    }
    float pr = pr0 + pr1, pz = pz0 + pz1, pn = pn0 + pn1;
    pr += __shfl_xor(pr, 1);
    pz += __shfl_xor(pz, 1);
    pn += __shfl_xor(pn, 1);
    float hnew = 0.f;
    if (part == 0) {
      float r = sigf(gi_r + pr + bh_r);
      float z = sigf(gi_z + pz + bh_z);
      float n = tanhfast(gi_n + r * (pn + bh_n));
      hnew = (1.f - z) * n + z * hprev;
      hprev = hnew;
      ob[((size_t)b * 1000 + t) * 256 + u] = f2bf(hnew);
      if (t == 999) hatt[b * 256 + u] = hnew;
    }
    // pack (h[u], h[u+1]) -> s_h2[cur^1][u>>1]; writer: tid%4==0 (u even, part0)
    float hother = __shfl_xor(hnew, 2);
    if ((tid & 3) == 0) s_h2[cur ^ 1][tid >> 2] = pk(hnew, hother);
    __syncthreads();
    cur ^= 1;
  }
}

// ---------------------------------------------------------------------------
// K4: snr GRU scans over B=32 steps; batch dim = T (independent per t).
//     64 WGs x 16 t-rows, grus_wih LDS-stationary, lsnr fused.
// ---------------------------------------------------------------------------
__global__ __launch_bounds__(256) void k_gru_snr(
    const u16* __restrict__ ob, const float* __restrict__ wih,
    const float* __restrict__ whh, const float* __restrict__ bih,
    const float* __restrict__ bhh, const float* __restrict__ fcw,
    const float* __restrict__ fcb,
    float* __restrict__ lsnr_out, float* __restrict__ hsnr_out)
{
  __shared__ float s_wi[48][260];
  __shared__ float s_wh[48][20];
  __shared__ float s_o[16][260];
  __shared__ float s_h[16][20];
  const int tid = threadIdx.x, wg = blockIdx.x;
  const int n0 = wg * 16;
  for (int i = tid; i < 48 * 256; i += 256) s_wi[i >> 8][i & 255] = wih[i];
  for (int i = tid; i < 768; i += 256) s_wh[i >> 4][i & 15] = whh[i];
  const int n = tid >> 4, u = tid & 15;
  const bool valid = (n0 + n) < 1000;
  s_h[n][u] = 0.f;
  float hcur = 0.f;
  const float bi_r = bih[u], bi_z = bih[16 + u], bi_n = bih[32 + u];
  const float bh_r = bhh[u], bh_z = bhh[16 + u], bh_n = bhh[32 + u];
  const float fw = fcw[u], fb = fcb[0];
  __syncthreads();
  for (int step = 0; step < 32; ++step) {
    for (int i = tid; i < 512; i += 256) {
      int nn = i >> 5, c8 = (i & 31) * 8;
      int row = n0 + nn;
      if (row < 1000) {
        u16x8 v = *(const u16x8*)(ob + ((size_t)step * 1000 + row) * 256 + c8);
        #pragma unroll
        for (int j = 0; j < 8; ++j) s_o[nn][c8 + j] = bf2f(v[j]);
      } else {
        #pragma unroll
        for (int j = 0; j < 8; ++j) s_o[nn][c8 + j] = 0.f;
      }
    }
    __syncthreads();
    float gr = bi_r, gz = bi_z, gn = bi_n;
    {
      const float4* o4 = (const float4*)&s_o[n][0];
      const float4* wr = (const float4*)&s_wi[u][0];
      const float4* wz = (const float4*)&s_wi[16 + u][0];
      const float4* wn = (const float4*)&s_wi[32 + u][0];
      #pragma unroll 4
      for (int k4 = 0; k4 < 64; ++k4) {
        float4 ov = o4[k4];
        float4 a = wr[k4], c = wz[k4], d = wn[k4];
        gr += ov.x*a.x + ov.y*a.y + ov.z*a.z + ov.w*a.w;
        gz += ov.x*c.x + ov.y*c.y + ov.z*c.z + ov.w*c.w;
        gn += ov.x*d.x + ov.y*d.y + ov.z*d.z + ov.w*d.w;
      }
    }
    float hr = bh_r, hz = bh_z, hn_ = bh_n;
    #pragma unroll
    for (int k = 0; k < 16; ++k) {
      float hv = s_h[n][k];
      hr  += s_wh[u][k] * hv;
      hz  += s_wh[16 + u][k] * hv;
      hn_ += s_wh[32 + u][k] * hv;
    }
    float r = sigf(gr + hr);
    float z = sigf(gz + hz);
    float nn2 = tanhfast(gn + r * hn_);
    float hnew = (1.f - z) * nn2 + z * hcur;
    __syncthreads();
    s_h[n][u] = hnew;
    hcur = hnew;
    float part = hnew * fw;
    #pragma unroll
    for (int m = 8; m >= 1; m >>= 1) part += __shfl_xor(part, m);
    if (u == 0 && valid) lsnr_out[step * 1000 + n0 + n] = sigf(part + fb) * 50.f - 15.f;
    __syncthreads();
  }
  if (valid) hsnr_out[(size_t)(n0 + n) * 16 + u] = hcur;
}

// ---------------------------------------------------------------------------
// K5: xe = LN(x1 + e); m = sigmoid(LN(conv2(xe)))
// ---------------------------------------------------------------------------
__global__ __launch_bounds__(256) void k_final(
    const u16* __restrict__ x1g, const u16* __restrict__ ob,
    const float* __restrict__ lng, const float* __restrict__ lnb,
    const float* __restrict__ c2w, const float* __restrict__ c2b,
    const float* __restrict__ g2, const float* __restrict__ be2,
    float* __restrict__ m_out)
{
  const int bt = blockIdx.x, tid = threadIdx.x;
  __shared__ float s_xe[8][34];
  __shared__ float s_y[32];
  const int c = tid >> 5, f = tid & 31;
  float v = bf2f(x1g[(size_t)bt * 256 + tid]) + bf2f(ob[(size_t)bt * 256 + tid]);
  float s = v, ss = v * v;
  #pragma unroll
  for (int m = 16; m >= 1; m >>= 1) { s += __shfl_xor(s, m); ss += __shfl_xor(ss, m); }
  float mu = s * (1.f/32.f), rs = rsqrtf(ss * (1.f/32.f) - mu * mu + 1e-5f);
  s_xe[c][1 + f] = (v - mu) * rs * lng[f] + lnb[f];
  if (tid < 8) { s_xe[tid][0] = 0.f; s_xe[tid][33] = 0.f; }
  __syncthreads();
  if (tid < 32) {
    float a = c2b[0];
    #pragma unroll
    for (int cc = 0; cc < 8; ++cc) {
      const float* wr = c2w + cc * 3;
      a += wr[0]*s_xe[cc][tid] + wr[1]*s_xe[cc][tid+1] + wr[2]*s_xe[cc][tid+2];
    }
    s_y[tid] = a;
  }
  __syncthreads();
  if (tid < 32) {
    float y = s_y[tid];
    float s2 = y, ss2 = y * y;
    #pragma unroll
    for (int m = 16; m >= 1; m >>= 1) { s2 += __shfl_xor(s2, m); ss2 += __shfl_xor(ss2, m); }
    float mu2 = s2 * (1.f/32.f), rs2 = rsqrtf(ss2 * (1.f/32.f) - mu2 * mu2 + 1e-5f);
    float yn = (y - mu2) * rs2 * g2[tid] + be2[tid];
    m_out[(size_t)bt * 32 + tid] = sigf(yn);
  }
}

// ---------------------------------------------------------------------------
extern "C" void kernel_launch(void* const* d_in, const int* in_sizes, int n_in,
                              void* d_out, int out_size, void* d_ws, size_t ws_size,
                              hipStream_t stream)
{
  const float* input = (const float*)d_in[0];
  const float* w0    = (const float*)d_in[1];
  const float* b0    = (const float*)d_in[2];
  const float* ln0g  = (const float*)d_in[3];
  const float* ln0b  = (const float*)d_in[4];
  const float* w1    = (const float*)d_in[5];
  const float* b1    = (const float*)d_in[6];
  const float* ln1g  = (const float*)d_in[7];
  const float* ln1b  = (const float*)d_in[8];
  const float* qw    = (const float*)d_in[9];
  const float* qb    = (const float*)d_in[10];
  const float* kw    = (const float*)d_in[11];
  const float* kb    = (const float*)d_in[12];
  const float* vw    = (const float*)d_in[13];
  const float* vb    = (const float*)d_in[14];
  const float* gwih  = (const float*)d_in[15];
  const float* gwhh  = (const float*)d_in[16];
  const float* gbih  = (const float*)d_in[17];
  const float* gbhh  = (const float*)d_in[18];
  const float* lng   = (const float*)d_in[19];
  const float* lnb   = (const float*)d_in[20];
  const float* swih  = (const float*)d_in[21];
  const float* swhh  = (const float*)d_in[22];
  const float* sbih  = (const float*)d_in[23];
  const float* sbhh  = (const float*)d_in[24];
  const float* fcw   = (const float*)d_in[25];
  const float* fcb   = (const float*)d_in[26];
  const float* c2w   = (const float*)d_in[27];
  const float* c2b   = (const float*)d_in[28];
  const float* ln2g  = (const float*)d_in[29];
  const float* ln2b  = (const float*)d_in[30];
  (void)in_sizes; (void)n_in; (void)out_size;

  char* ws = (char*)d_ws;
  size_t off = 0;
  auto take = [&](size_t bytes) -> void* {
    void* p = ws + off;
    off += (bytes + 255) & ~(size_t)255;
    return p;
  };
  u16* x1g = (u16*)take((size_t)32000 * 256 * 2);
  u16* ob  = (u16*)take((size_t)32000 * 256 * 2);

  // Adaptive sizing: GB = batch elements per GRU group; CH = frontend/gemm
  // chunk rows. Pick largest GB whose gih+gi staging fits in remaining ws.
  const size_t fixedoff = off;
  int GB = 32;
  while (GB > 1) {
    int ch = 6400; if (ch > GB * 1000) ch = ((GB * 1000 + 63) / 64) * 64;
    size_t need = fixedoff + ((size_t)GB * 1000 * 768 * 2 + 256)
                           + ((size_t)ch * 2048 * 2 + 256);
    if (need <= ws_size) break;
    GB >>= 1;
  }
  int CH = 6400; if (CH > GB * 1000) CH = ((GB * 1000 + 63) / 64) * 64;
  u16* gih = (u16*)take((size_t)GB * 1000 * 768 * 2);
  u16* gi  = (u16*)take((size_t)CH * 2048 * 2);

  float* out      = (float*)d_out;
  float* m_out    = out;                 // [32,1,1000,32] = 1,024,000
  float* lsnr_out = out + 1024000;       // [32,1000,1]    =    32,000
  float* hatt_out = out + 1056000;       // [1,32,256]     =     8,192
  float* hsnr_out = out + 1064192;       // [1,1000,16]    =    16,000

  const int NG = 32 / GB;
  for (int g = 0; g < NG; ++g) {
    const int row0 = g * GB * 1000, rows = GB * 1000;
    for (int c0 = 0; c0 < rows; c0 += CH) {
      const int Mc = (rows - c0 < CH) ? (rows - c0) : CH;
      k_frontend<<<Mc, 256, 0, stream>>>(input, w0, b0, ln0g, ln0b, w1, b1,
                                         ln1g, ln1b, qw, qb, kw, kb, vw, vb,
                                         row0 + c0, x1g, gi);
      dim3 gg((Mc + 63) / 64, 12);
      k_gemm_bias<<<gg, 256, 0, stream>>>(gi, gwih, gbih, gih + (size_t)c0 * 768, Mc);
    }
    k_gru_batch<<<GB, 512, 0, stream>>>(gih, gwhh, gbhh, ob, hatt_out, g * GB);
  }
  k_gru_snr<<<64, 256, 0, stream>>>(ob, swih, swhh, sbih, sbhh, fcw, fcb,
                                    lsnr_out, hsnr_out);
  k_final<<<32000, 256, 0, stream>>>(x1g, ob, lng, lnb, c2w, c2b, ln2g, ln2b, m_out);
}

// Round 6
// 2442.652 us; speedup vs baseline: 9.8238x; 1.5179x over previous
//
#include <hip/hip_runtime.h>

// ErbStage: conv0+LN+ReLU -> conv1+LN+ReLU -> spectral attention -> GRU(T=1000)
//           -> GRU(B=32 scan) + lsnr -> LN/conv2/LN/sigmoid mask.
//
// R5: (a) k_gemm_bias -> k_gemm_mfma (bf16 MFMA 16x16x32, 128x256 tile,
//         2x4 wave grid, W pre-converted to bf16 by k_wcvt);
//     (b) k_frontend scores/att phases restructured to float4 LDS reads +
//         padded s_q/s_k/s_v/s_sc layouts (kills 16-way write conflicts).

typedef unsigned short u16;
typedef u16 u16x8 __attribute__((ext_vector_type(8)));
typedef short s16x8 __attribute__((ext_vector_type(8)));
typedef float f32x4 __attribute__((ext_vector_type(4)));
typedef _Float16 h2t __attribute__((ext_vector_type(2)));

__device__ __forceinline__ float sigf(float x) { return 1.f / (1.f + __expf(-x)); }
__device__ __forceinline__ float tanhfast(float x) { return 2.f / (1.f + __expf(-2.f * x)) - 1.f; }
__device__ __forceinline__ float bf2f(u16 s) { union { unsigned u; float f; } x; x.u = ((unsigned)s) << 16; return x.f; }
__device__ __forceinline__ u16 f2bf(float f) {
  union { float f; unsigned u; } x; x.f = f;
  unsigned r = x.u + 0x7fffu + ((x.u >> 16) & 1u);
  return (u16)(r >> 16);
}
__device__ __forceinline__ h2t pk(float a, float b) {
  auto v = __builtin_amdgcn_cvt_pkrtz(a, b);
  union { decltype(v) i; h2t o; } u; u.i = v; return u.o;
}

// ---------------------------------------------------------------------------
// K0: one-time W f32 -> bf16 convert (768x2048 = 1.57M elems, 8/thread)
// ---------------------------------------------------------------------------
__global__ __launch_bounds__(256) void k_wcvt(const float* __restrict__ W,
                                              u16* __restrict__ Wb)
{
  const size_t i = ((size_t)blockIdx.x * 256 + threadIdx.x) * 8;
  float4 a = *(const float4*)(W + i);
  float4 b = *(const float4*)(W + i + 4);
  u16x8 o;
  o[0] = f2bf(a.x); o[1] = f2bf(a.y); o[2] = f2bf(a.z); o[3] = f2bf(a.w);
  o[4] = f2bf(b.x); o[5] = f2bf(b.y); o[6] = f2bf(b.z); o[7] = f2bf(b.w);
  *(u16x8*)(Wb + i) = o;
}

// ---------------------------------------------------------------------------
// K1: fused frontend per (b,t): conv0+LN+ReLU -> conv1+LN+ReLU (store x1 bf16)
//     -> q/k/v 1x3 convs -> QK^T/8 -> joint softmax(1024) -> att*V -> gi (bf16)
// ---------------------------------------------------------------------------
__global__ __launch_bounds__(256) void k_frontend(
    const float* __restrict__ in,
    const float* __restrict__ w0c, const float* __restrict__ b0c,
    const float* __restrict__ g0, const float* __restrict__ be0,
    const float* __restrict__ w1c, const float* __restrict__ b1c,
    const float* __restrict__ g1, const float* __restrict__ be1,
    const float* __restrict__ qw, const float* __restrict__ qb,
    const float* __restrict__ kw, const float* __restrict__ kb,
    const float* __restrict__ vw, const float* __restrict__ vb,
    int bt0, u16* __restrict__ x1g, u16* __restrict__ gi)
{
  const int bt = bt0 + blockIdx.x, tid = threadIdx.x;
  __shared__ float s_in[34];
  __shared__ float s_x0[16][34];
  __shared__ float s_x1[8][34];
  __shared__ float s_q[64][36];   // padded: write banks (4h+f)%32 spread
  __shared__ float s_k[64][36];
  __shared__ float s_v[32][68];
  __shared__ float s_sc[32][36];
  __shared__ float s_red[8];
  __shared__ float s_mu[16], s_rs[16];

  if (tid < 32) s_in[1 + tid] = in[(size_t)bt * 32 + tid];
  if (tid == 0) { s_in[0] = 0.f; s_in[33] = 0.f; }
  __syncthreads();

  // conv0 (1->16)
  #pragma unroll
  for (int i = 0; i < 2; ++i) {
    int o = tid + i * 256, c = o >> 5, f = o & 31;
    float a = b0c[c] + w0c[c*3]*s_in[f] + w0c[c*3+1]*s_in[f+1] + w0c[c*3+2]*s_in[f+2];
    s_x0[c][1 + f] = a;
  }
  __syncthreads();
  // ln0 stats: 16 channels x 16 threads
  {
    int c = tid >> 4, i = tid & 15;
    float a = s_x0[c][1 + i], b = s_x0[c][17 + i];
    float s = a + b, ss = a * a + b * b;
    #pragma unroll
    for (int m = 8; m >= 1; m >>= 1) { s += __shfl_xor(s, m); ss += __shfl_xor(ss, m); }
    if (i == 0) { float mu = s * (1.f/32.f); s_mu[c] = mu; s_rs[c] = rsqrtf(ss * (1.f/32.f) - mu*mu + 1e-5f); }
  }
  __syncthreads();
  #pragma unroll
  for (int i = 0; i < 2; ++i) {
    int o = tid + i * 256, c = o >> 5, f = o & 31;
    float v = (s_x0[c][1 + f] - s_mu[c]) * s_rs[c] * g0[f] + be0[f];
    s_x0[c][1 + f] = fmaxf(v, 0.f);
  }
  if (tid < 16) { s_x0[tid][0] = 0.f; s_x0[tid][33] = 0.f; }
  __syncthreads();

  // conv1 (16->8) + ln1 + relu; one thread per (c1,f)
  {
    int c = tid >> 5, f = tid & 31;
    float a = b1c[c];
    #pragma unroll
    for (int cc = 0; cc < 16; ++cc) {
      const float* wr = w1c + (c * 16 + cc) * 3;
      a += wr[0]*s_x0[cc][f] + wr[1]*s_x0[cc][f+1] + wr[2]*s_x0[cc][f+2];
    }
    float s = a, ss = a * a;
    #pragma unroll
    for (int m = 16; m >= 1; m >>= 1) { s += __shfl_xor(s, m); ss += __shfl_xor(ss, m); }
    float mu = s * (1.f/32.f), rs = rsqrtf(ss * (1.f/32.f) - mu*mu + 1e-5f);
    float v = fmaxf((a - mu) * rs * g1[f] + be1[f], 0.f);
    s_x1[c][1 + f] = v;
    x1g[(size_t)bt * 256 + tid] = f2bf(v);
  }
  if (tid < 8) { s_x1[tid][0] = 0.f; s_x1[tid][33] = 0.f; }
  __syncthreads();

  // q/k/v convs (8->64 each). thread: h = tid>>2, fg = tid&3, 8 f's each
  {
    int h = tid >> 2, fg = tid & 3;
    float aq[8], ak[8], av[8];
    float qbv = qb[h], kbv = kb[h], vbv = vb[h];
    #pragma unroll
    for (int i = 0; i < 8; ++i) { aq[i] = qbv; ak[i] = kbv; av[i] = vbv; }
    #pragma unroll
    for (int c = 0; c < 8; ++c) {
      const float* qr = qw + (h * 8 + c) * 3;
      const float* kr = kw + (h * 8 + c) * 3;
      const float* vr = vw + (h * 8 + c) * 3;
      float q0 = qr[0], q1 = qr[1], q2 = qr[2];
      float k0 = kr[0], k1 = kr[1], k2 = kr[2];
      float v0 = vr[0], v1 = vr[1], v2 = vr[2];
      #pragma unroll
      for (int i = 0; i < 8; ++i) {
        int f = fg + i * 4;
        float xa = s_x1[c][f], xb = s_x1[c][f+1], xc = s_x1[c][f+2];
        aq[i] += q0*xa + q1*xb + q2*xc;
        ak[i] += k0*xa + k1*xb + k2*xc;
        av[i] += v0*xa + v1*xb + v2*xc;
      }
    }
    #pragma unroll
    for (int i = 0; i < 8; ++i) {
      int f = fg + i * 4;
      s_q[h][f] = aq[i];
      s_k[h][f] = ak[i];
      s_v[f][h] = av[i];
    }
  }
  __syncthreads();

  // scores w[f][g] = sum_h q[h][f]*k[h][g] / 8
  // thread -> (f = tid>>3, 4 g's at gq*4): float4 k-reads, broadcast q-reads
  const int sf = tid >> 3, sgq = tid & 7;
  float sc0 = 0.f, sc1 = 0.f, sc2 = 0.f, sc3 = 0.f;
  #pragma unroll 8
  for (int h = 0; h < 64; ++h) {
    float q = s_q[h][sf];
    float4 k4 = *(const float4*)&s_k[h][sgq * 4];
    sc0 += q * k4.x; sc1 += q * k4.y; sc2 += q * k4.z; sc3 += q * k4.w;
  }
  sc0 *= 0.125f; sc1 *= 0.125f; sc2 *= 0.125f; sc3 *= 0.125f;
  // joint softmax over all 1024
  float mx = fmaxf(fmaxf(sc0, sc1), fmaxf(sc2, sc3));
  #pragma unroll
  for (int m = 32; m >= 1; m >>= 1) mx = fmaxf(mx, __shfl_xor(mx, m));
  if ((tid & 63) == 0) s_red[tid >> 6] = mx;
  __syncthreads();
  mx = fmaxf(fmaxf(s_red[0], s_red[1]), fmaxf(s_red[2], s_red[3]));
  sc0 = __expf(sc0 - mx); sc1 = __expf(sc1 - mx);
  sc2 = __expf(sc2 - mx); sc3 = __expf(sc3 - mx);
  float sm = sc0 + sc1 + sc2 + sc3;
  #pragma unroll
  for (int m = 32; m >= 1; m >>= 1) sm += __shfl_xor(sm, m);
  __syncthreads();
  if ((tid & 63) == 0) s_red[4 + (tid >> 6)] = sm;
  __syncthreads();
  float inv = 1.f / (s_red[4] + s_red[5] + s_red[6] + s_red[7]);
  {
    float4 o4; o4.x = sc0 * inv; o4.y = sc1 * inv; o4.z = sc2 * inv; o4.w = sc3 * inv;
    *(float4*)&s_sc[sf][sgq * 4] = o4;
  }
  __syncthreads();

  // att[f][h] = sum_g w[f][g]*v[g][h]; thread -> (f, 8 h's at hq*8)
  {
    const int f = tid >> 3, hq = tid & 7;
    float a0=0,a1=0,a2=0,a3=0,a4=0,a5=0,a6=0,a7=0;
    #pragma unroll 8
    for (int g = 0; g < 32; ++g) {
      float w = s_sc[f][g];
      float4 v0 = *(const float4*)&s_v[g][hq * 8];
      float4 v1 = *(const float4*)&s_v[g][hq * 8 + 4];
      a0 += w * v0.x; a1 += w * v0.y; a2 += w * v0.z; a3 += w * v0.w;
      a4 += w * v1.x; a5 += w * v1.y; a6 += w * v1.z; a7 += w * v1.w;
    }
    u16x8 ov;
    ov[0] = f2bf(a0); ov[1] = f2bf(a1); ov[2] = f2bf(a2); ov[3] = f2bf(a3);
    ov[4] = f2bf(a4); ov[5] = f2bf(a5); ov[6] = f2bf(a6); ov[7] = f2bf(a7);
    *(u16x8*)(gi + (size_t)blockIdx.x * 2048 + f * 64 + hq * 8) = ov;
  }
}

// ---------------------------------------------------------------------------
// K2: C[M,768](bf16) = A[M,2048](bf16) @ Wb[768,2048]^T(bf16) + bias
//     MFMA 16x16x32 bf16; BM=128, BN=256, BK=32; 512 thr = 2x4 wave grid,
//     64x64 wave tiles (4x4 mfma frags each). LDS rows padded to 40 bf16.
// ---------------------------------------------------------------------------
__global__ __launch_bounds__(512, 2) void k_gemm_mfma(
    const u16* __restrict__ A, const u16* __restrict__ Wb,
    const float* __restrict__ bias, u16* __restrict__ C, int M)
{
  __shared__ u16 lA[128][40];
  __shared__ u16 lB[256][40];
  const int tid = threadIdx.x;
  const int m0 = blockIdx.x * 128, n0 = blockIdx.y * 256;
  const int w = tid >> 6, l = tid & 63;
  const int wr = w >> 2, wc = w & 3;     // 2x4 wave grid
  const int fr = l & 15, fg = l >> 4;    // frag row/col, k-group
  f32x4 acc[4][4] = {};
  const int ar = tid >> 2, akc = tid & 3;   // A: 128 rows x 4 chunks of 8
  const int br = tid >> 1, bkc = tid & 1;   // B: 256 rows x 2 chunks of 16
  for (int k0 = 0; k0 < 2048; k0 += 32) {
    int am = m0 + ar;
    u16x8 av = (u16x8)(u16)0;
    if (am < M) av = *(const u16x8*)(A + (size_t)am * 2048 + k0 + akc * 8);
    *(u16x8*)&lA[ar][akc * 8] = av;
    const u16* bp = Wb + (size_t)(n0 + br) * 2048 + k0 + bkc * 16;
    u16x8 bv0 = *(const u16x8*)bp;
    u16x8 bv1 = *(const u16x8*)(bp + 8);
    *(u16x8*)&lB[br][bkc * 16] = bv0;
    *(u16x8*)&lB[br][bkc * 16 + 8] = bv1;
    __syncthreads();
    #pragma unroll
    for (int mi = 0; mi < 4; ++mi) {
      s16x8 afr = *(const s16x8*)&lA[wr * 64 + mi * 16 + fr][fg * 8];
      #pragma unroll
      for (int ni = 0; ni < 4; ++ni) {
        s16x8 bfr = *(const s16x8*)&lB[wc * 64 + ni * 16 + fr][fg * 8];
        acc[mi][ni] = __builtin_amdgcn_mfma_f32_16x16x32_bf16(afr, bfr, acc[mi][ni], 0, 0, 0);
      }
    }
    __syncthreads();
  }
  // D layout: col = l&15, row = (l>>4)*4 + i
  #pragma unroll
  for (int mi = 0; mi < 4; ++mi) {
    #pragma unroll
    for (int ni = 0; ni < 4; ++ni) {
      int col = n0 + wc * 64 + ni * 16 + (l & 15);
      float bv = bias[col];
      #pragma unroll
      for (int i = 0; i < 4; ++i) {
        int row = m0 + wr * 64 + mi * 16 + (l >> 4) * 4 + i;
        if (row < M) C[(size_t)row * 768 + col] = f2bf(acc[mi][ni][i] + bv);
      }
    }
  }
}

// ---------------------------------------------------------------------------
// K3: main GRU over T=1000 (unchanged from R4).
// ---------------------------------------------------------------------------
__global__ __launch_bounds__(512, 2) void k_gru_batch(
    const u16* __restrict__ gih, const float* __restrict__ whh,
    const float* __restrict__ bhh, u16* __restrict__ ob,
    float* __restrict__ hatt, int b0)
{
  __shared__ h2t s_h2[2][128];
  const int tid = threadIdx.x;
  const int u = tid >> 1, part = tid & 1;
  const int bl = blockIdx.x;
  const int b = b0 + bl;

  h2t wr_[64], wz_[64], wn_[64];
  {
    const float4* r4 = (const float4*)(whh + (size_t)(      u) * 256 + part * 128);
    const float4* z4 = (const float4*)(whh + (size_t)(256 + u) * 256 + part * 128);
    const float4* n4 = (const float4*)(whh + (size_t)(512 + u) * 256 + part * 128);
    #pragma unroll
    for (int j = 0; j < 32; ++j) {
      float4 a = r4[j];
      wr_[2*j]   = pk(a.x, a.y);
      wr_[2*j+1] = pk(a.z, a.w);
      float4 c = z4[j];
      wz_[2*j]   = pk(c.x, c.y);
      wz_[2*j+1] = pk(c.z, c.w);
      float4 d = n4[j];
      wn_[2*j]   = pk(d.x, d.y);
      wn_[2*j+1] = pk(d.z, d.w);
    }
  }
  float bh_r = 0.f, bh_z = 0.f, bh_n = 0.f;
  if (part == 0) { bh_r = bhh[u]; bh_z = bhh[256 + u]; bh_n = bhh[512 + u]; }
  if (tid < 128) s_h2[0][tid] = pk(0.f, 0.f);
  __syncthreads();

  float hprev = 0.f;
  int cur = 0;
  union H4 { uint4 u4; h2t h[4]; };
  for (int t = 0; t < 1000; ++t) {
    float gi_r = 0.f, gi_z = 0.f, gi_n = 0.f;
    if (part == 0) {
      const u16* gr_ = gih + ((size_t)bl * 1000 + t) * 768;
      gi_r = bf2f(gr_[u]); gi_z = bf2f(gr_[256 + u]); gi_n = bf2f(gr_[512 + u]);
    }
    const uint4* hp = (const uint4*)&s_h2[cur][part * 64];
    float pr0 = 0.f, pr1 = 0.f, pz0 = 0.f, pz1 = 0.f, pn0 = 0.f, pn1 = 0.f;
    #pragma unroll
    for (int k4 = 0; k4 < 16; ++k4) {
      H4 hv; hv.u4 = hp[k4];
      pr0 = __builtin_amdgcn_fdot2(hv.h[0], wr_[4*k4+0], pr0, false);
      pz0 = __builtin_amdgcn_fdot2(hv.h[0], wz_[4*k4+0], pz0, false);
      pn0 = __builtin_amdgcn_fdot2(hv.h[0], wn_[4*k4+0], pn0, false);
      pr1 = __builtin_amdgcn_fdot2(hv.h[1], wr_[4*k4+1], pr1, false);
      pz1 = __builtin_amdgcn_fdot2(hv.h[1], wz_[4*k4+1], pz1, false);
      pn1 = __builtin_amdgcn_fdot2(hv.h[1], wn_[4*k4+1], pn1, false);
      pr0 = __builtin_amdgcn_fdot2(hv.h[2], wr_[4*k4+2], pr0, false);
      pz0 = __builtin_amdgcn_fdot2(hv.h[2], wz_[4*k4+2], pz0, false);
      pn0 = __builtin_amdgcn_fdot2(hv.h[2], wn_[4*k4+2], pn0, false);
      pr1 = __builtin_amdgcn_fdot2(hv.h[3], wr_[4*k4+3], pr1, false);
      pz1 = __builtin_amdgcn_fdot2(hv.h[3], wz_[4*k4+3], pz1, false);
      pn1 = __builtin_amdgcn_fdot2(hv.h[3], wn_[4*k4+3], pn1, false);
    }
    float pr = pr0 + pr1, pz = pz0 + pz1, pn = pn0 + pn1;
    pr += __shfl_xor(pr, 1);
    pz += __shfl_xor(pz, 1);
    pn += __shfl_xor(pn, 1);
    float hnew = 0.f;
    if (part == 0) {
      float r = sigf(gi_r + pr + bh_r);
      float z = sigf(gi_z + pz + bh_z);
      float n = tanhfast(gi_n + r * (pn + bh_n));
      hnew = (1.f - z) * n + z * hprev;
      hprev = hnew;
      ob[((size_t)b * 1000 + t) * 256 + u] = f2bf(hnew);
      if (t == 999) hatt[b * 256 + u] = hnew;
    }
    float hother = __shfl_xor(hnew, 2);
    if ((tid & 3) == 0) s_h2[cur ^ 1][tid >> 2] = pk(hnew, hother);
    __syncthreads();
    cur ^= 1;
  }
}

// ---------------------------------------------------------------------------
// K4: snr GRU scans over B=32 steps; batch dim = T (independent per t).
// ---------------------------------------------------------------------------
__global__ __launch_bounds__(256) void k_gru_snr(
    const u16* __restrict__ ob, const float* __restrict__ wih,
    const float* __restrict__ whh, const float* __restrict__ bih,
    const float* __restrict__ bhh, const float* __restrict__ fcw,
    const float* __restrict__ fcb,
    float* __restrict__ lsnr_out, float* __restrict__ hsnr_out)
{
  __shared__ float s_wi[48][260];
  __shared__ float s_wh[48][20];
  __shared__ float s_o[16][260];
  __shared__ float s_h[16][20];
  const int tid = threadIdx.x, wg = blockIdx.x;
  const int n0 = wg * 16;
  for (int i = tid; i < 48 * 256; i += 256) s_wi[i >> 8][i & 255] = wih[i];
  for (int i = tid; i < 768; i += 256) s_wh[i >> 4][i & 15] = whh[i];
  const int n = tid >> 4, u = tid & 15;
  const bool valid = (n0 + n) < 1000;
  s_h[n][u] = 0.f;
  float hcur = 0.f;
  const float bi_r = bih[u], bi_z = bih[16 + u], bi_n = bih[32 + u];
  const float bh_r = bhh[u], bh_z = bhh[16 + u], bh_n = bhh[32 + u];
  const float fw = fcw[u], fb = fcb[0];
  __syncthreads();
  for (int step = 0; step < 32; ++step) {
    for (int i = tid; i < 512; i += 256) {
      int nn = i >> 5, c8 = (i & 31) * 8;
      int row = n0 + nn;
      if (row < 1000) {
        u16x8 v = *(const u16x8*)(ob + ((size_t)step * 1000 + row) * 256 + c8);
        #pragma unroll
        for (int j = 0; j < 8; ++j) s_o[nn][c8 + j] = bf2f(v[j]);
      } else {
        #pragma unroll
        for (int j = 0; j < 8; ++j) s_o[nn][c8 + j] = 0.f;
      }
    }
    __syncthreads();
    float gr = bi_r, gz = bi_z, gn = bi_n;
    {
      const float4* o4 = (const float4*)&s_o[n][0];
      const float4* wr = (const float4*)&s_wi[u][0];
      const float4* wz = (const float4*)&s_wi[16 + u][0];
      const float4* wn = (const float4*)&s_wi[32 + u][0];
      #pragma unroll 4
      for (int k4 = 0; k4 < 64; ++k4) {
        float4 ov = o4[k4];
        float4 a = wr[k4], c = wz[k4], d = wn[k4];
        gr += ov.x*a.x + ov.y*a.y + ov.z*a.z + ov.w*a.w;
        gz += ov.x*c.x + ov.y*c.y + ov.z*c.z + ov.w*c.w;
        gn += ov.x*d.x + ov.y*d.y + ov.z*d.z + ov.w*d.w;
      }
    }
    float hr = bh_r, hz = bh_z, hn_ = bh_n;
    #pragma unroll
    for (int k = 0; k < 16; ++k) {
      float hv = s_h[n][k];
      hr  += s_wh[u][k] * hv;
      hz  += s_wh[16 + u][k] * hv;
      hn_ += s_wh[32 + u][k] * hv;
    }
    float r = sigf(gr + hr);
    float z = sigf(gz + hz);
    float nn2 = tanhfast(gn + r * hn_);
    float hnew = (1.f - z) * nn2 + z * hcur;
    __syncthreads();
    s_h[n][u] = hnew;
    hcur = hnew;
    float part = hnew * fw;
    #pragma unroll
    for (int m = 8; m >= 1; m >>= 1) part += __shfl_xor(part, m);
    if (u == 0 && valid) lsnr_out[step * 1000 + n0 + n] = sigf(part + fb) * 50.f - 15.f;
    __syncthreads();
  }
  if (valid) hsnr_out[(size_t)(n0 + n) * 16 + u] = hcur;
}

// ---------------------------------------------------------------------------
// K5: xe = LN(x1 + e); m = sigmoid(LN(conv2(xe)))
// ---------------------------------------------------------------------------
__global__ __launch_bounds__(256) void k_final(
    const u16* __restrict__ x1g, const u16* __restrict__ ob,
    const float* __restrict__ lng, const float* __restrict__ lnb,
    const float* __restrict__ c2w, const float* __restrict__ c2b,
    const float* __restrict__ g2, const float* __restrict__ be2,
    float* __restrict__ m_out)
{
  const int bt = blockIdx.x, tid = threadIdx.x;
  __shared__ float s_xe[8][34];
  __shared__ float s_y[32];
  const int c = tid >> 5, f = tid & 31;
  float v = bf2f(x1g[(size_t)bt * 256 + tid]) + bf2f(ob[(size_t)bt * 256 + tid]);
  float s = v, ss = v * v;
  #pragma unroll
  for (int m = 16; m >= 1; m >>= 1) { s += __shfl_xor(s, m); ss += __shfl_xor(ss, m); }
  float mu = s * (1.f/32.f), rs = rsqrtf(ss * (1.f/32.f) - mu * mu + 1e-5f);
  s_xe[c][1 + f] = (v - mu) * rs * lng[f] + lnb[f];
  if (tid < 8) { s_xe[tid][0] = 0.f; s_xe[tid][33] = 0.f; }
  __syncthreads();
  if (tid < 32) {
    float a = c2b[0];
    #pragma unroll
    for (int cc = 0; cc < 8; ++cc) {
      const float* wr = c2w + cc * 3;
      a += wr[0]*s_xe[cc][tid] + wr[1]*s_xe[cc][tid+1] + wr[2]*s_xe[cc][tid+2];
    }
    s_y[tid] = a;
  }
  __syncthreads();
  if (tid < 32) {
    float y = s_y[tid];
    float s2 = y, ss2 = y * y;
    #pragma unroll
    for (int m = 16; m >= 1; m >>= 1) { s2 += __shfl_xor(s2, m); ss2 += __shfl_xor(ss2, m); }
    float mu2 = s2 * (1.f/32.f), rs2 = rsqrtf(ss2 * (1.f/32.f) - mu2 * mu2 + 1e-5f);
    float yn = (y - mu2) * rs2 * g2[tid] + be2[tid];
    m_out[(size_t)bt * 32 + tid] = sigf(yn);
  }
}

// ---------------------------------------------------------------------------
extern "C" void kernel_launch(void* const* d_in, const int* in_sizes, int n_in,
                              void* d_out, int out_size, void* d_ws, size_t ws_size,
                              hipStream_t stream)
{
  const float* input = (const float*)d_in[0];
  const float* w0    = (const float*)d_in[1];
  const float* b0    = (const float*)d_in[2];
  const float* ln0g  = (const float*)d_in[3];
  const float* ln0b  = (const float*)d_in[4];
  const float* w1    = (const float*)d_in[5];
  const float* b1    = (const float*)d_in[6];
  const float* ln1g  = (const float*)d_in[7];
  const float* ln1b  = (const float*)d_in[8];
  const float* qw    = (const float*)d_in[9];
  const float* qb    = (const float*)d_in[10];
  const float* kw    = (const float*)d_in[11];
  const float* kb    = (const float*)d_in[12];
  const float* vw    = (const float*)d_in[13];
  const float* vb    = (const float*)d_in[14];
  const float* gwih  = (const float*)d_in[15];
  const float* gwhh  = (const float*)d_in[16];
  const float* gbih  = (const float*)d_in[17];
  const float* gbhh  = (const float*)d_in[18];
  const float* lng   = (const float*)d_in[19];
  const float* lnb   = (const float*)d_in[20];
  const float* swih  = (const float*)d_in[21];
  const float* swhh  = (const float*)d_in[22];
  const float* sbih  = (const float*)d_in[23];
  const float* sbhh  = (const float*)d_in[24];
  const float* fcw   = (const float*)d_in[25];
  const float* fcb   = (const float*)d_in[26];
  const float* c2w   = (const float*)d_in[27];
  const float* c2b   = (const float*)d_in[28];
  const float* ln2g  = (const float*)d_in[29];
  const float* ln2b  = (const float*)d_in[30];
  (void)in_sizes; (void)n_in; (void)out_size;

  char* ws = (char*)d_ws;
  size_t off = 0;
  auto take = [&](size_t bytes) -> void* {
    void* p = ws + off;
    off += (bytes + 255) & ~(size_t)255;
    return p;
  };
  u16* x1g = (u16*)take((size_t)32000 * 256 * 2);
  u16* ob  = (u16*)take((size_t)32000 * 256 * 2);
  u16* gwb = (u16*)take((size_t)768 * 2048 * 2);    // bf16 gruo_wih

  const size_t fixedoff = off;
  int GB = 32;
  while (GB > 1) {
    int ch = 6400; if (ch > GB * 1000) ch = ((GB * 1000 + 63) / 64) * 64;
    size_t need = fixedoff + ((size_t)GB * 1000 * 768 * 2 + 256)
                           + ((size_t)ch * 2048 * 2 + 256);
    if (need <= ws_size) break;
    GB >>= 1;
  }
  int CH = 6400; if (CH > GB * 1000) CH = ((GB * 1000 + 63) / 64) * 64;
  u16* gih = (u16*)take((size_t)GB * 1000 * 768 * 2);
  u16* gi  = (u16*)take((size_t)CH * 2048 * 2);

  float* out      = (float*)d_out;
  float* m_out    = out;                 // [32,1,1000,32] = 1,024,000
  float* lsnr_out = out + 1024000;       // [32,1000,1]    =    32,000
  float* hatt_out = out + 1056000;       // [1,32,256]     =     8,192
  float* hsnr_out = out + 1064192;       // [1,1000,16]    =    16,000

  k_wcvt<<<768, 256, 0, stream>>>(gwih, gwb);   // 768*2048/8/256 = 768 blocks

  const int NG = 32 / GB;
  for (int g = 0; g < NG; ++g) {
    const int row0 = g * GB * 1000, rows = GB * 1000;
    for (int c0 = 0; c0 < rows; c0 += CH) {
      const int Mc = (rows - c0 < CH) ? (rows - c0) : CH;
      k_frontend<<<Mc, 256, 0, stream>>>(input, w0, b0, ln0g, ln0b, w1, b1,
                                         ln1g, ln1b, qw, qb, kw, kb, vw, vb,
                                         row0 + c0, x1g, gi);
      dim3 gg((Mc + 127) / 128, 3);
      k_gemm_mfma<<<gg, 512, 0, stream>>>(gi, gwb, gbih, gih + (size_t)c0 * 768, Mc);
    }
    k_gru_batch<<<GB, 512, 0, stream>>>(gih, gwhh, gbhh, ob, hatt_out, g * GB);
  }
  k_gru_snr<<<64, 256, 0, stream>>>(ob, swih, swhh, sbih, sbhh, fcw, fcb,
                                    lsnr_out, hsnr_out);
  k_final<<<32000, 256, 0, stream>>>(x1g, ob, lng, lnb, c2w, c2b, ln2g, ln2b, m_out);
}